// Round 2
// baseline (875.241 us; speedup 1.0000x reference)
//
#include <hip/hip_runtime.h>
#include <stdint.h>

typedef __attribute__((ext_vector_type(4))) float  f32x4;
typedef __attribute__((ext_vector_type(8))) short  s16x8;
typedef __attribute__((ext_vector_type(4))) short  s16x4;
typedef __attribute__((ext_vector_type(8))) __bf16 bf16x8;

#define DEV __device__ __forceinline__

// sign of e_a * e_b in Cl(4,1), METRIC=(1,1,1,1,-1): C[a,b,a^b]
DEV float blade_sign(int a, int b){
    int s = 0, t = a >> 1;
    while (t){ s += __popc(t & b); t >>= 1; }
    float sg = (s & 1) ? -1.0f : 1.0f;
    return ((a & b) & 16) ? -sg : sg;
}
DEV short f2bf(float v){                       // RNE float->bf16 bits
    union { float f; uint32_t u; } x; x.f = v;
    uint32_t r = x.u + 0x7fffu + ((x.u >> 16) & 1u);
    return (short)(r >> 16);
}
DEV float bf2f(short b){
    union { uint32_t u; float f; } x; x.u = ((uint32_t)(uint16_t)b) << 16;
    return x.f;
}

// ---------------- cast x (f32) -> hi/lo bf16, 8 elems/thread ----------------
__global__ __launch_bounds__(256) void cast_split(const float* __restrict__ in,
                                                  short* __restrict__ oh,
                                                  short* __restrict__ ol){
    const size_t idx = (size_t)blockIdx.x * 256 + threadIdx.x;
    const float4* p = reinterpret_cast<const float4*>(in) + idx * 2;
    float4 a = p[0], b = p[1];
    float v[8] = {a.x,a.y,a.z,a.w,b.x,b.y,b.z,b.w};
    s16x8 h, l;
    #pragma unroll
    for (int e = 0; e < 8; ++e){
        short hh = f2bf(v[e]);
        h[e] = hh;
        l[e] = f2bf(v[e] - bf2f(hh));
    }
    *reinterpret_cast<s16x8*>(oh + idx * 8) = h;
    *reinterpret_cast<s16x8*>(ol + idx * 8) = l;
}

// ------- build WmatT: WmT[o*32+kb][i*32+l] = W[o,i,kb^l]*C[kb^l,l,kb] -------
template<bool SPLIT>
__global__ __launch_bounds__(256) void build_wmat(const float* __restrict__ W,
                                                  short* __restrict__ WmTh,
                                                  short* __restrict__ WmTl){
    const int idx = blockIdx.x * 256 + threadIdx.x;     // 2M threads, 8 elems each
    const int n  = idx >> 9;          // output row (o*32+kb), 0..4095
    const int kg = idx & 511;         // 8-elem group within row
    const int o = n >> 5, kb = n & 31;
    const int i = kg >> 2, l0 = (kg & 3) * 8;
    const float* wrow = W + (size_t)(o * 128 + i) * 32;
    s16x8 vh, vl;
    #pragma unroll
    for (int e = 0; e < 8; ++e){
        const int l = l0 + e, j = kb ^ l;
        const float v = wrow[j] * blade_sign(j, l);
        const short hh = f2bf(v);
        vh[e] = hh;
        if constexpr (SPLIT) vl[e] = f2bf(v - bf2f(hh));
    }
    *reinterpret_cast<s16x8*>(WmTh + (size_t)n * 4096 + kg * 8) = vh;
    if constexpr (SPLIT)
        *reinterpret_cast<s16x8*>(WmTl + (size_t)n * 4096 + kg * 8) = vl;
}

// ------------- per-(b,h,s) norms over 512 features, hi+lo inputs -------------
__global__ __launch_bounds__(256) void row_norms(const short* __restrict__ Qh,
                                                 const short* __restrict__ Ql,
                                                 const short* __restrict__ Kh,
                                                 const short* __restrict__ Kl,
                                                 float* __restrict__ Nq,
                                                 float* __restrict__ Nk){
    const int row  = blockIdx.x * 4 + (threadIdx.x >> 6);   // 16384 rows
    const int lane = threadIdx.x & 63;
    const int b = row >> 13, h = (row >> 10) & 7, s = row & 1023;
    const size_t off = ((size_t)(b * 1024 + s)) * 4096 + h * 512 + lane * 8;
    s16x8 qh = *reinterpret_cast<const s16x8*>(Qh + off);
    s16x8 ql = *reinterpret_cast<const s16x8*>(Ql + off);
    s16x8 kh = *reinterpret_cast<const s16x8*>(Kh + off);
    s16x8 kl = *reinterpret_cast<const s16x8*>(Kl + off);
    float sq = 0.f, sk = 0.f;
    #pragma unroll
    for (int e = 0; e < 8; ++e){
        float fq = bf2f(qh[e]) + bf2f(ql[e]); sq = fmaf(fq, fq, sq);
        float fk = bf2f(kh[e]) + bf2f(kl[e]); sk = fmaf(fk, fk, sk);
    }
    #pragma unroll
    for (int m = 1; m < 64; m <<= 1){
        sq += __shfl_xor(sq, m);
        sk += __shfl_xor(sk, m);
    }
    if (lane == 0){ Nq[row] = sq; Nk[row] = sk; }
}

// -------- softmax per row, in place: read 1024 f32, write 1024 bf16 at row head --------
__global__ __launch_bounds__(256) void softmax_rows(float* __restrict__ Sc){
    const int row  = blockIdx.x * 4 + (threadIdx.x >> 6);   // 16384 rows
    const int lane = threadIdx.x & 63;
    float* p = Sc + (size_t)row * 1024;
    float v[16];
    float mx = -3.0e38f;
    #pragma unroll
    for (int j = 0; j < 16; ++j){ v[j] = p[lane + j * 64]; mx = fmaxf(mx, v[j]); }
    #pragma unroll
    for (int m = 1; m < 64; m <<= 1) mx = fmaxf(mx, __shfl_xor(mx, m));
    float sum = 0.f;
    #pragma unroll
    for (int j = 0; j < 16; ++j){ v[j] = __expf(v[j] - mx); sum += v[j]; }
    #pragma unroll
    for (int m = 1; m < 64; m <<= 1) sum += __shfl_xor(sum, m);
    const float inv = 1.0f / sum;
    short* pb = reinterpret_cast<short*>(p);   // reads above already in registers
    #pragma unroll
    for (int j = 0; j < 16; ++j) pb[lane + j * 64] = f2bf(v[j] * inv);
}

#define GLOAD_LDS(gp, lp) \
    __builtin_amdgcn_global_load_lds( \
        (const __attribute__((address_space(1))) void*)(const void*)(gp), \
        (__attribute__((address_space(3))) void*)(void*)(lp), 16, 0, 0)

// =======================================================================
// Plain bf16 GEMM (m97 structure): 128x128 tile, BK=32, 4 waves.
// C[m][n] = sum_k A[m][k] * Bt[n][k]
// EPI: 2=v-proj(norm, V^T bf16 store)  3=final(norm, f32)  5=PV(bf16, batched)
// =======================================================================
template<int EPI>
__global__ __launch_bounds__(256) void versor_gemm(
    const short* __restrict__ Abase, int lda,
    const short* __restrict__ Bbase, int ldb,
    int K, void* __restrict__ OutP)
{
    __shared__ short As[128 * 32];
    __shared__ short Bs[128 * 32];

    const int tid  = threadIdx.x;
    const int lane = tid & 63;
    const int wid  = tid >> 6;
    const int wr   = wid >> 1;
    const int wc   = wid & 1;
    const int bn = blockIdx.x, bm = blockIdx.y, z = blockIdx.z;

    const short* A = Abase;
    const short* B = Bbase;
    if constexpr (EPI == 5){                       // PV: probs + V^T slices
        A += (size_t)z * 1024 * 2048;
        B += (size_t)z * 512 * 1024;
    }

    const int row0 = bm * 128;
    const int col0 = bn * 128;

    const int slot0 = (wid * 2 + 0) * 64 + lane;
    const int slot1 = (wid * 2 + 1) * 64 + lane;
    const int ar0 = slot0 >> 2, ac0 = (slot0 & 3) * 8;
    const int ar1 = slot1 >> 2, ac1 = (slot1 & 3) * 8;
    const short* gA0 = A + (size_t)(row0 + ar0) * lda + ac0;
    const short* gA1 = A + (size_t)(row0 + ar1) * lda + ac1;
    const short* gB0 = B + (size_t)(col0 + ar0) * ldb + ac0;
    const short* gB1 = B + (size_t)(col0 + ar1) * ldb + ac1;
    short* lA0 = As + (wid * 2 + 0) * 512;
    short* lA1 = As + (wid * 2 + 1) * 512;
    short* lB0 = Bs + (wid * 2 + 0) * 512;
    short* lB1 = Bs + (wid * 2 + 1) * 512;

    f32x4 acc[4][4];
    #pragma unroll
    for (int i = 0; i < 4; ++i)
        #pragma unroll
        for (int j = 0; j < 4; ++j)
            acc[i][j] = (f32x4){0.f, 0.f, 0.f, 0.f};

    const int fragoff = (lane & 15) * 32 + (lane >> 4) * 8;

    for (int kt = 0; kt < K; kt += 32){
        __syncthreads();
        GLOAD_LDS(gA0 + kt, lA0);
        GLOAD_LDS(gA1 + kt, lA1);
        GLOAD_LDS(gB0 + kt, lB0);
        GLOAD_LDS(gB1 + kt, lB1);
        __syncthreads();

        bf16x8 af[4], bfv[4];
        #pragma unroll
        for (int i = 0; i < 4; ++i){
            af[i]  = *reinterpret_cast<const bf16x8*>(As + (wr * 64 + i * 16) * 32 + fragoff);
            bfv[i] = *reinterpret_cast<const bf16x8*>(Bs + (wc * 64 + i * 16) * 32 + fragoff);
        }
        #pragma unroll
        for (int mi = 0; mi < 4; ++mi)
            #pragma unroll
            for (int ni = 0; ni < 4; ++ni)
                acc[mi][ni] = __builtin_amdgcn_mfma_f32_16x16x32_bf16(
                    af[mi], bfv[ni], acc[mi][ni], 0, 0, 0);
    }

    const int rb = row0 + wr * 64 + (lane >> 4) * 4;
    const int cb = col0 + wc * 64 + (lane & 15);

    if constexpr (EPI == 2 || EPI == 3){
        #pragma unroll
        for (int mi = 0; mi < 4; ++mi){
            #pragma unroll
            for (int g = 0; g < 2; ++g){
                f32x4 a0 = acc[mi][2 * g], a1 = acc[mi][2 * g + 1];
                f32x4 ss = a0 * a0 + a1 * a1;
                #pragma unroll
                for (int m = 1; m < 16; m <<= 1){
                    ss.x += __shfl_xor(ss.x, m);
                    ss.y += __shfl_xor(ss.y, m);
                    ss.z += __shfl_xor(ss.z, m);
                    ss.w += __shfl_xor(ss.w, m);
                }
                f32x4 inv;
                inv.x = 1.0f / sqrtf(ss.x * 0.03125f + 1e-6f);
                inv.y = 1.0f / sqrtf(ss.y * 0.03125f + 1e-6f);
                inv.z = 1.0f / sqrtf(ss.z * 0.03125f + 1e-6f);
                inv.w = 1.0f / sqrtf(ss.w * 0.03125f + 1e-6f);
                acc[mi][2 * g]     = a0 * inv;
                acc[mi][2 * g + 1] = a1 * inv;
            }
        }
    }

    if constexpr (EPI == 2){   // V^T store: (b,h,f,t), 4 consecutive t per lane
        short* Ob = (short*)OutP;
        #pragma unroll
        for (int mi = 0; mi < 4; ++mi){
            const int r = rb + mi * 16;
            const int b = r >> 10, t = r & 1023;
            #pragma unroll
            for (int ni = 0; ni < 4; ++ni){
                const int c = cb + ni * 16;
                const int h = c >> 9, f = c & 511;
                s16x4 pv;
                #pragma unroll
                for (int j = 0; j < 4; ++j) pv[j] = f2bf(acc[mi][ni][j]);
                *reinterpret_cast<s16x4*>(Ob + ((size_t)((b * 8 + h) * 512 + f)) * 1024 + t) = pv;
            }
        }
    }
    if constexpr (EPI == 3){
        float* Of = (float*)OutP;
        #pragma unroll
        for (int mi = 0; mi < 4; ++mi)
            #pragma unroll
            for (int ni = 0; ni < 4; ++ni)
                #pragma unroll
                for (int j = 0; j < 4; ++j)
                    Of[(size_t)(rb + mi * 16 + j) * 4096 + (cb + ni * 16)] = acc[mi][ni][j];
    }
    if constexpr (EPI == 5){   // PV out -> attnout[(b*1024+s)*4096 + h*512 + f] bf16
        short* Ob = (short*)OutP;
        const int b = z >> 3, h = z & 7;
        #pragma unroll
        for (int mi = 0; mi < 4; ++mi)
            #pragma unroll
            for (int ni = 0; ni < 4; ++ni)
                #pragma unroll
                for (int j = 0; j < 4; ++j)
                    Ob[(size_t)(b * 1024 + rb + mi * 16 + j) * 4096 + h * 512 + (cb + ni * 16)]
                        = f2bf(acc[mi][ni][j]);
    }
}

// =======================================================================
// Split (hi/lo) 3-term GEMM: C = (Ah+Al)*(Bh+Bl)^T ~= Ah*Bh + Al*Bh + Ah*Bl
// EPI: 0=k-proj(norm, hi/lo store)  1=q-proj(norm, *SIG, hi/lo store)
//      4=scores(torque epilogue, f32, batched over z=(b,h))
// =======================================================================
template<int EPI>
__global__ __launch_bounds__(256) void versor_gemm_split(
    const short* __restrict__ AhB, const short* __restrict__ AlB, int lda,
    const short* __restrict__ BhB, const short* __restrict__ BlB, int ldb,
    int K, void* __restrict__ OutP, int osplit,
    const float* __restrict__ NqP, const float* __restrict__ NkP,
    const float* __restrict__ LamP)
{
    __shared__ short Ash[128 * 32];
    __shared__ short Asl[128 * 32];
    __shared__ short Bsh[128 * 32];
    __shared__ short Bsl[128 * 32];

    const int tid  = threadIdx.x;
    const int lane = tid & 63;
    const int wid  = tid >> 6;
    const int wr   = wid >> 1;
    const int wc   = wid & 1;
    const int bn = blockIdx.x, bm = blockIdx.y, z = blockIdx.z;

    const short* Ah = AhB; const short* Al = AlB;
    const short* Bh = BhB; const short* Bl = BlB;
    if constexpr (EPI == 4){
        const int b = z >> 3, h = z & 7;
        const size_t off = (size_t)b * 1024 * 4096 + (size_t)h * 512;
        Ah += off; Al += off; Bh += off; Bl += off;
    }

    const int row0 = bm * 128;
    const int col0 = bn * 128;

    const int slot0 = (wid * 2 + 0) * 64 + lane;
    const int slot1 = (wid * 2 + 1) * 64 + lane;
    const int ar0 = slot0 >> 2, ac0 = (slot0 & 3) * 8;
    const int ar1 = slot1 >> 2, ac1 = (slot1 & 3) * 8;
    const size_t aoff0 = (size_t)(row0 + ar0) * lda + ac0;
    const size_t aoff1 = (size_t)(row0 + ar1) * lda + ac1;
    const size_t boff0 = (size_t)(col0 + ar0) * ldb + ac0;
    const size_t boff1 = (size_t)(col0 + ar1) * ldb + ac1;
    const int lo0 = (wid * 2 + 0) * 512;
    const int lo1 = (wid * 2 + 1) * 512;

    f32x4 acc[4][4];
    #pragma unroll
    for (int i = 0; i < 4; ++i)
        #pragma unroll
        for (int j = 0; j < 4; ++j)
            acc[i][j] = (f32x4){0.f, 0.f, 0.f, 0.f};

    const int fragoff = (lane & 15) * 32 + (lane >> 4) * 8;

    for (int kt = 0; kt < K; kt += 32){
        __syncthreads();
        GLOAD_LDS(Ah + aoff0 + kt, Ash + lo0);
        GLOAD_LDS(Ah + aoff1 + kt, Ash + lo1);
        GLOAD_LDS(Al + aoff0 + kt, Asl + lo0);
        GLOAD_LDS(Al + aoff1 + kt, Asl + lo1);
        GLOAD_LDS(Bh + boff0 + kt, Bsh + lo0);
        GLOAD_LDS(Bh + boff1 + kt, Bsh + lo1);
        GLOAD_LDS(Bl + boff0 + kt, Bsl + lo0);
        GLOAD_LDS(Bl + boff1 + kt, Bsl + lo1);
        __syncthreads();

        bf16x8 afh[4], afl[4], bfh[4], bfl[4];
        #pragma unroll
        for (int i = 0; i < 4; ++i){
            const int ra = (wr * 64 + i * 16) * 32 + fragoff;
            const int rbo = (wc * 64 + i * 16) * 32 + fragoff;
            afh[i] = *reinterpret_cast<const bf16x8*>(Ash + ra);
            afl[i] = *reinterpret_cast<const bf16x8*>(Asl + ra);
            bfh[i] = *reinterpret_cast<const bf16x8*>(Bsh + rbo);
            bfl[i] = *reinterpret_cast<const bf16x8*>(Bsl + rbo);
        }
        #pragma unroll
        for (int mi = 0; mi < 4; ++mi)
            #pragma unroll
            for (int ni = 0; ni < 4; ++ni){
                acc[mi][ni] = __builtin_amdgcn_mfma_f32_16x16x32_bf16(
                    afh[mi], bfh[ni], acc[mi][ni], 0, 0, 0);
                acc[mi][ni] = __builtin_amdgcn_mfma_f32_16x16x32_bf16(
                    afl[mi], bfh[ni], acc[mi][ni], 0, 0, 0);
                acc[mi][ni] = __builtin_amdgcn_mfma_f32_16x16x32_bf16(
                    afh[mi], bfl[ni], acc[mi][ni], 0, 0, 0);
            }
    }

    const int rb = row0 + wr * 64 + (lane >> 4) * 4;
    const int cb = col0 + wc * 64 + (lane & 15);

    if constexpr (EPI <= 1){
        // normalize each 32-col blade group to unit RMS
        #pragma unroll
        for (int mi = 0; mi < 4; ++mi){
            #pragma unroll
            for (int g = 0; g < 2; ++g){
                f32x4 a0 = acc[mi][2 * g], a1 = acc[mi][2 * g + 1];
                f32x4 ss = a0 * a0 + a1 * a1;
                #pragma unroll
                for (int m = 1; m < 16; m <<= 1){
                    ss.x += __shfl_xor(ss.x, m);
                    ss.y += __shfl_xor(ss.y, m);
                    ss.z += __shfl_xor(ss.z, m);
                    ss.w += __shfl_xor(ss.w, m);
                }
                f32x4 inv;
                inv.x = 1.0f / sqrtf(ss.x * 0.03125f + 1e-6f);
                inv.y = 1.0f / sqrtf(ss.y * 0.03125f + 1e-6f);
                inv.z = 1.0f / sqrtf(ss.z * 0.03125f + 1e-6f);
                inv.w = 1.0f / sqrtf(ss.w * 0.03125f + 1e-6f);
                acc[mi][2 * g]     = a0 * inv;
                acc[mi][2 * g + 1] = a1 * inv;
            }
        }
        if constexpr (EPI == 1){   // fold SIG (blade square signs) into q
            const float sg0 = blade_sign(lane & 15, lane & 15);
            const float sg1 = blade_sign(16 | (lane & 15), 16 | (lane & 15));
            #pragma unroll
            for (int mi = 0; mi < 4; ++mi)
                #pragma unroll
                for (int ni = 0; ni < 4; ++ni)
                    acc[mi][ni] *= (ni & 1) ? sg1 : sg0;
        }
        short* Oh = (short*)OutP;
        short* Ol = Oh + osplit;
        #pragma unroll
        for (int mi = 0; mi < 4; ++mi)
            #pragma unroll
            for (int ni = 0; ni < 4; ++ni)
                #pragma unroll
                for (int j = 0; j < 4; ++j){
                    const float v = acc[mi][ni][j];
                    const short hh = f2bf(v);
                    const size_t idx = (size_t)(rb + mi * 16 + j) * 4096 + (cb + ni * 16);
                    Oh[idx] = hh;
                    Ol[idx] = f2bf(v - bf2f(hh));
                }
    }
    if constexpr (EPI == 4){   // scores + torque
        float* Of = (float*)OutP + (size_t)z * 1024 * 1024;
        const float lam = *LamP;
        const float* nq = NqP + z * 1024;
        const float* nk = NkP + z * 1024;
        #pragma unroll
        for (int mi = 0; mi < 4; ++mi)
            #pragma unroll
            for (int j = 0; j < 4; ++j){
                const int r = rb + mi * 16 + j;
                const float qn = nq[r];
                #pragma unroll
                for (int ni = 0; ni < 4; ++ni){
                    const int c = cb + ni * 16;
                    const float sc = acc[mi][ni][j];
                    const float tq = sqrtf(fmaxf(qn * nk[c] - sc * sc, 0.0f) + 1e-6f);
                    Of[(size_t)r * 1024 + c] = 0.25f * (sc + lam * tq);
                }
            }
    }
}

// =======================================================================
extern "C" void kernel_launch(void* const* d_in, const int* in_sizes, int n_in,
                              void* d_out, int out_size, void* d_ws, size_t ws_size,
                              hipStream_t stream)
{
    (void)in_sizes; (void)n_in; (void)out_size; (void)ws_size;
    const float* x   = (const float*)d_in[0];
    const float* Wq  = (const float*)d_in[1];
    const float* Wk  = (const float*)d_in[2];
    const float* Wv  = (const float*)d_in[3];
    const float* Wo  = (const float*)d_in[4];
    const float* lam = (const float*)d_in[5];
    float* out = (float*)d_out;
    char*  ws  = (char*)d_ws;

    // workspace layout (~160.2 MB peak)
    short* Xh   = (short*)(ws);                            // 16 MB; later attn-out
    short* Xl   = (short*)(ws + (16u  << 20));             // 16 MB; later V^T
    short* WmTh = (short*)(ws + (32u  << 20));             // 32 MB; later Sc[0:32MB]
    short* WmTl = (short*)(ws + (64u  << 20));             // 32 MB; later Sc[32:64MB]
    short* Qh   = (short*)(ws + (96u  << 20));             // 16 MB
    short* Ql   = (short*)(ws + (112u << 20));             // 16 MB
    short* Kh   = (short*)(ws + (128u << 20));             // 16 MB
    short* Kl   = (short*)(ws + (144u << 20));             // 16 MB
    float* Nq   = (float*)(ws + (160u << 20));             // 64 KB
    float* Nk   = (float*)(ws + (160u << 20) + (64u << 10));
    float* Sc   = (float*)(ws + (32u  << 20));             // 64 MB (overlays WmT)
    short* Vt   = Xl;                                       // 16 MB (overlays Xl)
    short* Attn = Xh;                                       // 16 MB (overlays Xh)
    const int OSPLIT = 2048 * 4096;

    dim3 blk(256);
    cast_split<<<4096, blk, 0, stream>>>(x, Xh, Xl);

    dim3 gproj(32, 16, 1);   // N=4096/128, M=2048/128
    build_wmat<true><<<8192, blk, 0, stream>>>(Wq, WmTh, WmTl);
    versor_gemm_split<1><<<gproj, blk, 0, stream>>>(Xh, Xl, 4096, WmTh, WmTl, 4096,
                                                    4096, Qh, OSPLIT, nullptr, nullptr, nullptr);
    build_wmat<true><<<8192, blk, 0, stream>>>(Wk, WmTh, WmTl);
    versor_gemm_split<0><<<gproj, blk, 0, stream>>>(Xh, Xl, 4096, WmTh, WmTl, 4096,
                                                    4096, Kh, OSPLIT, nullptr, nullptr, nullptr);
    // V projection: plain bf16 (not softmax-amplified). Writes Vt over Xl (Xl dead now).
    build_wmat<false><<<8192, blk, 0, stream>>>(Wv, WmTh, nullptr);
    versor_gemm<2><<<gproj, blk, 0, stream>>>(Xh, 4096, WmTh, 4096, 4096, Vt);

    row_norms<<<4096, blk, 0, stream>>>(Qh, Ql, Kh, Kl, Nq, Nk);

    dim3 gsc(8, 8, 16);      // N=1024/128, M=1024/128, 16 (b,h) batches
    versor_gemm_split<4><<<gsc, blk, 0, stream>>>(Qh, Ql, 4096, Kh, Kl, 4096,
                                                  512, Sc, 0, Nq, Nk, lam);
    softmax_rows<<<4096, blk, 0, stream>>>(Sc);

    dim3 gpv(4, 8, 16);      // N=512/128, M=1024/128, 16 batches
    versor_gemm<5><<<gpv, blk, 0, stream>>>((const short*)Sc, 2048, Vt, 1024, 1024, Attn);

    build_wmat<false><<<8192, blk, 0, stream>>>(Wo, WmTh, nullptr);
    versor_gemm<3><<<gproj, blk, 0, stream>>>(Attn, 4096, WmTh, 4096, 4096, out);
}

// Round 3
// 650.429 us; speedup vs baseline: 1.3456x; 1.3456x over previous
//
#include <hip/hip_runtime.h>
#include <stdint.h>

typedef __attribute__((ext_vector_type(4))) float    f32x4;
typedef __attribute__((ext_vector_type(8))) short    s16x8;
typedef __attribute__((ext_vector_type(4))) short    s16x4;
typedef __attribute__((ext_vector_type(8))) _Float16 f16x8;

#define DEV __device__ __forceinline__

// sign of e_a * e_b in Cl(4,1), METRIC=(1,1,1,1,-1): C[a,b,a^b]
DEV float blade_sign(int a, int b){
    int s = 0, t = a >> 1;
    while (t){ s += __popc(t & b); t >>= 1; }
    float sg = (s & 1) ? -1.0f : 1.0f;
    return ((a & b) & 16) ? -sg : sg;
}
DEV short f2h(float v){
    _Float16 h = (_Float16)v;                 // RNE f32->f16
    return __builtin_bit_cast(short, h);
}
DEV float h2f(short b){
    return (float)__builtin_bit_cast(_Float16, b);
}

// ---------------- cast x (f32) -> f16, 8 elems/thread ----------------
__global__ __launch_bounds__(256) void cast_f32_f16(const float* __restrict__ in,
                                                    short* __restrict__ out){
    const size_t idx = (size_t)blockIdx.x * 256 + threadIdx.x;
    const float4* p = reinterpret_cast<const float4*>(in) + idx * 2;
    float4 a = p[0], b = p[1];
    s16x8 o;
    o[0]=f2h(a.x); o[1]=f2h(a.y); o[2]=f2h(a.z); o[3]=f2h(a.w);
    o[4]=f2h(b.x); o[5]=f2h(b.y); o[6]=f2h(b.z); o[7]=f2h(b.w);
    *reinterpret_cast<s16x8*>(out + idx * 8) = o;
}

// ------- build WmatT f16: WmT[o*32+kb][i*32+l] = W[o,i,kb^l]*C[kb^l,l,kb] -------
__global__ __launch_bounds__(256) void build_wmat(const float* __restrict__ W,
                                                  short* __restrict__ WmT){
    const int idx = blockIdx.x * 256 + threadIdx.x;     // 2M threads, 8 elems each
    const int n  = idx >> 9;          // output row (o*32+kb), 0..4095
    const int kg = idx & 511;         // 8-elem group within row
    const int o = n >> 5, kb = n & 31;
    const int i = kg >> 2, l0 = (kg & 3) * 8;
    const float* wrow = W + (size_t)(o * 128 + i) * 32;
    s16x8 v;
    #pragma unroll
    for (int e = 0; e < 8; ++e){
        const int l = l0 + e, j = kb ^ l;
        v[e] = f2h(wrow[j] * blade_sign(j, l));
    }
    *reinterpret_cast<s16x8*>(WmT + (size_t)n * 4096 + kg * 8) = v;
}

// ---------------- per-(b,h,s) norms over 512 features (q and k) ----------------
__global__ __launch_bounds__(256) void row_norms(const short* __restrict__ Q,
                                                 const short* __restrict__ Kq,
                                                 float* __restrict__ Nq,
                                                 float* __restrict__ Nk){
    const int row  = blockIdx.x * 4 + (threadIdx.x >> 6);   // 16384 rows
    const int lane = threadIdx.x & 63;
    const int b = row >> 13, h = (row >> 10) & 7, s = row & 1023;
    const size_t off = ((size_t)(b * 1024 + s)) * 4096 + h * 512 + lane * 8;
    s16x8 a = *reinterpret_cast<const s16x8*>(Q + off);
    s16x8 c = *reinterpret_cast<const s16x8*>(Kq + off);
    float sq = 0.f, sk = 0.f;
    #pragma unroll
    for (int e = 0; e < 8; ++e){
        float fa = h2f(a[e]); sq = fmaf(fa, fa, sq);
        float fc = h2f(c[e]); sk = fmaf(fc, fc, sk);
    }
    #pragma unroll
    for (int m = 1; m < 64; m <<= 1){
        sq += __shfl_xor(sq, m);
        sk += __shfl_xor(sk, m);
    }
    if (lane == 0){ Nq[row] = sq; Nk[row] = sk; }
}

// -------- softmax per row, in place: read 1024 f32, write 1024 f16 at row head --------
__global__ __launch_bounds__(256) void softmax_rows(float* __restrict__ Sc){
    const int row  = blockIdx.x * 4 + (threadIdx.x >> 6);   // 16384 rows
    const int lane = threadIdx.x & 63;
    float* p = Sc + (size_t)row * 1024;
    float v[16];
    float mx = -3.0e38f;
    #pragma unroll
    for (int j = 0; j < 16; ++j){ v[j] = p[lane + j * 64]; mx = fmaxf(mx, v[j]); }
    #pragma unroll
    for (int m = 1; m < 64; m <<= 1) mx = fmaxf(mx, __shfl_xor(mx, m));
    float sum = 0.f;
    #pragma unroll
    for (int j = 0; j < 16; ++j){ v[j] = __expf(v[j] - mx); sum += v[j]; }
    #pragma unroll
    for (int m = 1; m < 64; m <<= 1) sum += __shfl_xor(sum, m);
    const float inv = 1.0f / sum;
    short* pb = reinterpret_cast<short*>(p);   // reads above already in registers
    #pragma unroll
    for (int j = 0; j < 16; ++j) pb[lane + j * 64] = f2h(v[j] * inv);
}

#define GLOAD_LDS(gp, lp) \
    __builtin_amdgcn_global_load_lds( \
        (const __attribute__((address_space(1))) void*)(const void*)(gp), \
        (__attribute__((address_space(3))) void*)(void*)(lp), 16, 0, 0)

// =======================================================================
// Generic f16 MFMA GEMM, m97 structure: 128x128 tile, BK=32, 4 waves,
// single-buffer LDS, global_load_lds width-16 staging, 16x16x32 MFMA.
// C[m][n] = sum_k A[m][k] * Bt[n][k]   (both operands K-contiguous)
// EPI: 0=k-proj(f16,norm)  1=q-proj(f16,norm,*SIG)  2=v-proj(f16,norm,V^T store)
//      3=final(f32,norm)   4=scores(torque epilogue, f32, batched)
//      5=PV(f16, batched, head-offset store)
// =======================================================================
template<int EPI>
__global__ __launch_bounds__(256) void versor_gemm(
    const short* __restrict__ Abase, int lda,
    const short* __restrict__ Bbase, int ldb,
    int K, void* __restrict__ OutP,
    const float* __restrict__ NqP, const float* __restrict__ NkP,
    const float* __restrict__ LamP)
{
    __shared__ short As[128 * 32];
    __shared__ short Bs[128 * 32];

    const int tid  = threadIdx.x;
    const int lane = tid & 63;
    const int wid  = tid >> 6;
    const int wr   = wid >> 1;       // wave row (0..1), 64 rows each
    const int wc   = wid & 1;        // wave col (0..1), 64 cols each
    const int bn = blockIdx.x, bm = blockIdx.y, z = blockIdx.z;

    const short* A = Abase;
    const short* B = Bbase;
    if constexpr (EPI == 4){                       // scores: per-(b,h) slices of q,k
        const int b = z >> 3, h = z & 7;
        const size_t off = (size_t)b * 1024 * 4096 + (size_t)h * 512;
        A += off; B += off;
    }
    if constexpr (EPI == 5){                       // PV: probs + V^T slices
        A += (size_t)z * 1024 * 2048;
        B += (size_t)z * 512 * 1024;
    }

    const int row0 = bm * 128;
    const int col0 = bn * 128;

    // staging: 512 16B-slots per tile; slot = (wid*2+t)*64 + lane; row=slot>>2
    const int slot0 = (wid * 2 + 0) * 64 + lane;
    const int slot1 = (wid * 2 + 1) * 64 + lane;
    const int ar0 = slot0 >> 2, ac0 = (slot0 & 3) * 8;
    const int ar1 = slot1 >> 2, ac1 = (slot1 & 3) * 8;
    const short* gA0 = A + (size_t)(row0 + ar0) * lda + ac0;
    const short* gA1 = A + (size_t)(row0 + ar1) * lda + ac1;
    const short* gB0 = B + (size_t)(col0 + ar0) * ldb + ac0;
    const short* gB1 = B + (size_t)(col0 + ar1) * ldb + ac1;
    short* lA0 = As + (wid * 2 + 0) * 512;
    short* lA1 = As + (wid * 2 + 1) * 512;
    short* lB0 = Bs + (wid * 2 + 0) * 512;
    short* lB1 = Bs + (wid * 2 + 1) * 512;

    f32x4 acc[4][4];
    #pragma unroll
    for (int i = 0; i < 4; ++i)
        #pragma unroll
        for (int j = 0; j < 4; ++j)
            acc[i][j] = (f32x4){0.f, 0.f, 0.f, 0.f};

    const int fragoff = (lane & 15) * 32 + (lane >> 4) * 8;  // shorts, within 16-row subtile

    for (int kt = 0; kt < K; kt += 32){
        __syncthreads();
        GLOAD_LDS(gA0 + kt, lA0);
        GLOAD_LDS(gA1 + kt, lA1);
        GLOAD_LDS(gB0 + kt, lB0);
        GLOAD_LDS(gB1 + kt, lB1);
        __syncthreads();

        f16x8 af[4], bfv[4];
        #pragma unroll
        for (int i = 0; i < 4; ++i){
            af[i]  = *reinterpret_cast<const f16x8*>(As + (wr * 64 + i * 16) * 32 + fragoff);
            bfv[i] = *reinterpret_cast<const f16x8*>(Bs + (wc * 64 + i * 16) * 32 + fragoff);
        }
        #pragma unroll
        for (int mi = 0; mi < 4; ++mi)
            #pragma unroll
            for (int ni = 0; ni < 4; ++ni)
                acc[mi][ni] = __builtin_amdgcn_mfma_f32_16x16x32_f16(
                    af[mi], bfv[ni], acc[mi][ni], 0, 0, 0);
    }

    // ---------------- epilogue ----------------
    const int rb = row0 + wr * 64 + (lane >> 4) * 4;   // + mi*16 + j
    const int cb = col0 + wc * 64 + (lane & 15);       // + ni*16

    if constexpr (EPI <= 3){
        // normalize each 32-col blade group to unit RMS (over blades)
        #pragma unroll
        for (int mi = 0; mi < 4; ++mi){
            #pragma unroll
            for (int g = 0; g < 2; ++g){
                f32x4 a0 = acc[mi][2 * g], a1 = acc[mi][2 * g + 1];
                f32x4 ss = a0 * a0 + a1 * a1;
                #pragma unroll
                for (int m = 1; m < 16; m <<= 1){
                    ss.x += __shfl_xor(ss.x, m);
                    ss.y += __shfl_xor(ss.y, m);
                    ss.z += __shfl_xor(ss.z, m);
                    ss.w += __shfl_xor(ss.w, m);
                }
                f32x4 inv;
                inv.x = 1.0f / sqrtf(ss.x * 0.03125f + 1e-6f);
                inv.y = 1.0f / sqrtf(ss.y * 0.03125f + 1e-6f);
                inv.z = 1.0f / sqrtf(ss.z * 0.03125f + 1e-6f);
                inv.w = 1.0f / sqrtf(ss.w * 0.03125f + 1e-6f);
                acc[mi][2 * g]     = a0 * inv;
                acc[mi][2 * g + 1] = a1 * inv;
            }
        }
    }
    if constexpr (EPI == 1){   // fold SIG (blade square signs) into q
        const float sg0 = blade_sign(lane & 15, lane & 15);
        const float sg1 = blade_sign(16 | (lane & 15), 16 | (lane & 15));
        #pragma unroll
        for (int mi = 0; mi < 4; ++mi)
            #pragma unroll
            for (int ni = 0; ni < 4; ++ni)
                acc[mi][ni] *= (ni & 1) ? sg1 : sg0;
    }

    if constexpr (EPI == 0 || EPI == 1){
        short* Ob = (short*)OutP;
        #pragma unroll
        for (int mi = 0; mi < 4; ++mi)
            #pragma unroll
            for (int ni = 0; ni < 4; ++ni)
                #pragma unroll
                for (int j = 0; j < 4; ++j)
                    Ob[(size_t)(rb + mi * 16 + j) * 4096 + (cb + ni * 16)] = f2h(acc[mi][ni][j]);
    }
    if constexpr (EPI == 2){   // V^T store: (b,h,f,t), 4 consecutive t per lane
        short* Ob = (short*)OutP;
        #pragma unroll
        for (int mi = 0; mi < 4; ++mi){
            const int r = rb + mi * 16;
            const int b = r >> 10, t = r & 1023;
            #pragma unroll
            for (int ni = 0; ni < 4; ++ni){
                const int c = cb + ni * 16;
                const int h = c >> 9, f = c & 511;
                s16x4 pv;
                #pragma unroll
                for (int j = 0; j < 4; ++j) pv[j] = f2h(acc[mi][ni][j]);
                *reinterpret_cast<s16x4*>(Ob + ((size_t)((b * 8 + h) * 512 + f)) * 1024 + t) = pv;
            }
        }
    }
    if constexpr (EPI == 3){
        float* Of = (float*)OutP;
        #pragma unroll
        for (int mi = 0; mi < 4; ++mi)
            #pragma unroll
            for (int ni = 0; ni < 4; ++ni)
                #pragma unroll
                for (int j = 0; j < 4; ++j)
                    Of[(size_t)(rb + mi * 16 + j) * 4096 + (cb + ni * 16)] = acc[mi][ni][j];
    }
    if constexpr (EPI == 4){   // scores + torque
        float* Of = (float*)OutP + (size_t)z * 1024 * 1024;
        const float lam = *LamP;
        const float* nq = NqP + z * 1024;
        const float* nk = NkP + z * 1024;
        #pragma unroll
        for (int mi = 0; mi < 4; ++mi)
            #pragma unroll
            for (int j = 0; j < 4; ++j){
                const int r = rb + mi * 16 + j;
                const float qn = nq[r];
                #pragma unroll
                for (int ni = 0; ni < 4; ++ni){
                    const int c = cb + ni * 16;
                    const float sc = acc[mi][ni][j];
                    const float tq = sqrtf(fmaxf(qn * nk[c] - sc * sc, 0.0f) + 1e-6f);
                    Of[(size_t)r * 1024 + c] = 0.25f * (sc + lam * tq);
                }
            }
    }
    if constexpr (EPI == 5){   // PV out -> attnout[(b*1024+s)*4096 + h*512 + f] f16
        short* Ob = (short*)OutP;
        const int b = z >> 3, h = z & 7;
        #pragma unroll
        for (int mi = 0; mi < 4; ++mi)
            #pragma unroll
            for (int ni = 0; ni < 4; ++ni)
                #pragma unroll
                for (int j = 0; j < 4; ++j)
                    Ob[(size_t)(b * 1024 + rb + mi * 16 + j) * 4096 + h * 512 + (cb + ni * 16)]
                        = f2h(acc[mi][ni][j]);
    }
}

// =======================================================================
extern "C" void kernel_launch(void* const* d_in, const int* in_sizes, int n_in,
                              void* d_out, int out_size, void* d_ws, size_t ws_size,
                              hipStream_t stream)
{
    (void)in_sizes; (void)n_in; (void)out_size; (void)ws_size;
    const float* x   = (const float*)d_in[0];
    const float* Wq  = (const float*)d_in[1];
    const float* Wk  = (const float*)d_in[2];
    const float* Wv  = (const float*)d_in[3];
    const float* Wo  = (const float*)d_in[4];
    const float* lam = (const float*)d_in[5];
    float* out = (float*)d_out;
    char*  ws  = (char*)d_ws;

    // workspace layout (162 MB peak; identical to proven R1 layout)
    short* Xf  = (short*)(ws);                            // 16 MB; reused as attn-out
    short* WmT = (short*)(ws + (16u << 20));              // 32 MB, rebuilt per projection
    short* Qf  = (short*)(ws + (48u << 20));              // 16 MB
    short* Kf  = (short*)(ws + (64u << 20));              // 16 MB
    short* Vt  = (short*)(ws + (80u << 20));              // 16 MB (B,H,512,1024) f16
    float* Nq  = (float*)(ws + (96u << 20));              // 64 KB
    float* Nk  = (float*)(ws + (96u << 20) + (1u << 20)); // 64 KB
    float* Sc  = (float*)(ws + (98u << 20));              // 64 MB (probs f16 in place)

    dim3 blk(256);
    cast_f32_f16<<<4096, blk, 0, stream>>>(x, Xf);

    dim3 gproj(32, 16, 1);   // N=4096/128, M=2048/128
    build_wmat<<<8192, blk, 0, stream>>>(Wq, WmT);
    versor_gemm<1><<<gproj, blk, 0, stream>>>(Xf, 4096, WmT, 4096, 4096, Qf, nullptr, nullptr, nullptr);
    build_wmat<<<8192, blk, 0, stream>>>(Wk, WmT);
    versor_gemm<0><<<gproj, blk, 0, stream>>>(Xf, 4096, WmT, 4096, 4096, Kf, nullptr, nullptr, nullptr);
    build_wmat<<<8192, blk, 0, stream>>>(Wv, WmT);
    versor_gemm<2><<<gproj, blk, 0, stream>>>(Xf, 4096, WmT, 4096, 4096, Vt, nullptr, nullptr, nullptr);

    row_norms<<<4096, blk, 0, stream>>>(Qf, Kf, Nq, Nk);

    dim3 gsc(8, 8, 16);      // N=1024/128, M=1024/128, 16 (b,h) batches
    versor_gemm<4><<<gsc, blk, 0, stream>>>(Qf, 4096, Kf, 4096, 512, Sc, Nq, Nk, lam);
    softmax_rows<<<4096, blk, 0, stream>>>(Sc);

    dim3 gpv(4, 8, 16);      // N=512/128, M=1024/128, 16 batches
    versor_gemm<5><<<gpv, blk, 0, stream>>>((const short*)Sc, 2048, Vt, 1024, 1024, Xf, nullptr, nullptr, nullptr);

    build_wmat<<<8192, blk, 0, stream>>>(Wo, WmT);
    versor_gemm<3><<<gproj, blk, 0, stream>>>(Xf, 4096, WmT, 4096, 4096, out, nullptr, nullptr, nullptr);
}

// Round 4
// 611.987 us; speedup vs baseline: 1.4302x; 1.0628x over previous
//
#include <hip/hip_runtime.h>
#include <stdint.h>

typedef __attribute__((ext_vector_type(4))) float    f32x4;
typedef __attribute__((ext_vector_type(8))) short    s16x8;
typedef __attribute__((ext_vector_type(4))) short    s16x4;
typedef __attribute__((ext_vector_type(8))) _Float16 f16x8;

#define DEV __device__ __forceinline__

// sign of e_a * e_b in Cl(4,1), METRIC=(1,1,1,1,-1): C[a,b,a^b]
DEV float blade_sign(int a, int b){
    int s = 0, t = a >> 1;
    while (t){ s += __popc(t & b); t >>= 1; }
    float sg = (s & 1) ? -1.0f : 1.0f;
    return ((a & b) & 16) ? -sg : sg;
}
DEV short f2h(float v){
    _Float16 h = (_Float16)v;                 // RNE f32->f16
    return __builtin_bit_cast(short, h);
}
DEV float h2f(short b){
    return (float)__builtin_bit_cast(_Float16, b);
}

// ---------------- cast x (f32) -> f16, 8 elems/thread ----------------
__global__ __launch_bounds__(256) void cast_f32_f16(const float* __restrict__ in,
                                                    short* __restrict__ out){
    const size_t idx = (size_t)blockIdx.x * 256 + threadIdx.x;
    const float4* p = reinterpret_cast<const float4*>(in) + idx * 2;
    float4 a = p[0], b = p[1];
    s16x8 o;
    o[0]=f2h(a.x); o[1]=f2h(a.y); o[2]=f2h(a.z); o[3]=f2h(a.w);
    o[4]=f2h(b.x); o[5]=f2h(b.y); o[6]=f2h(b.z); o[7]=f2h(b.w);
    *reinterpret_cast<s16x8*>(out + idx * 8) = o;
}

// ------- build WmatT f16: WmT[o*32+kb][i*32+l] = W[o,i,kb^l]*C[kb^l,l,kb] -------
DEV void build_wmat_body(const float* __restrict__ W, short* __restrict__ WmT,
                         int idx){
    const int n  = idx >> 9;          // output row (o*32+kb), 0..4095
    const int kg = idx & 511;         // 8-elem group within row
    const int o = n >> 5, kb = n & 31;
    const int i = kg >> 2, l0 = (kg & 3) * 8;
    const float* wrow = W + (size_t)(o * 128 + i) * 32;
    s16x8 v;
    #pragma unroll
    for (int e = 0; e < 8; ++e){
        const int l = l0 + e, j = kb ^ l;
        v[e] = f2h(wrow[j] * blade_sign(j, l));
    }
    *reinterpret_cast<s16x8*>(WmT + (size_t)n * 4096 + kg * 8) = v;
}

__global__ __launch_bounds__(256) void build_wmat(const float* __restrict__ W,
                                                  short* __restrict__ WmT){
    build_wmat_body(W, WmT, blockIdx.x * 256 + threadIdx.x);
}

__global__ __launch_bounds__(256) void build_wmat3(const float* __restrict__ Wq,
                                                   const float* __restrict__ Wk,
                                                   const float* __restrict__ Wv,
                                                   short* __restrict__ WmT3){
    const int w = blockIdx.y;
    const float* W = (w == 0) ? Wq : ((w == 1) ? Wk : Wv);
    build_wmat_body(W, WmT3 + (size_t)w * 4096 * 4096,
                    blockIdx.x * 256 + threadIdx.x);
}

// ---------------- per-(b,h,s) norms over 512 features (q and k) ----------------
__global__ __launch_bounds__(256) void row_norms(const short* __restrict__ Q,
                                                 const short* __restrict__ Kq,
                                                 float* __restrict__ Nq,
                                                 float* __restrict__ Nk){
    const int row  = blockIdx.x * 4 + (threadIdx.x >> 6);   // 16384 rows
    const int lane = threadIdx.x & 63;
    const int b = row >> 13, h = (row >> 10) & 7, s = row & 1023;
    const size_t off = ((size_t)(b * 1024 + s)) * 4096 + h * 512 + lane * 8;
    s16x8 a = *reinterpret_cast<const s16x8*>(Q + off);
    s16x8 c = *reinterpret_cast<const s16x8*>(Kq + off);
    float sq = 0.f, sk = 0.f;
    #pragma unroll
    for (int e = 0; e < 8; ++e){
        float fa = h2f(a[e]); sq = fmaf(fa, fa, sq);
        float fc = h2f(c[e]); sk = fmaf(fc, fc, sk);
    }
    #pragma unroll
    for (int m = 1; m < 64; m <<= 1){
        sq += __shfl_xor(sq, m);
        sk += __shfl_xor(sk, m);
    }
    if (lane == 0){ Nq[row] = sq; Nk[row] = sk; }
}

// -------- softmax per row, in place: read 1024 f32, write 1024 f16 at row head --------
__global__ __launch_bounds__(256) void softmax_rows(float* __restrict__ Sc){
    const int row  = blockIdx.x * 4 + (threadIdx.x >> 6);   // 16384 rows
    const int lane = threadIdx.x & 63;
    float* p = Sc + (size_t)row * 1024;
    float v[16];
    float mx = -3.0e38f;
    #pragma unroll
    for (int j = 0; j < 16; ++j){ v[j] = p[lane + j * 64]; mx = fmaxf(mx, v[j]); }
    #pragma unroll
    for (int m = 1; m < 64; m <<= 1) mx = fmaxf(mx, __shfl_xor(mx, m));
    float sum = 0.f;
    #pragma unroll
    for (int j = 0; j < 16; ++j){ v[j] = __expf(v[j] - mx); sum += v[j]; }
    #pragma unroll
    for (int m = 1; m < 64; m <<= 1) sum += __shfl_xor(sum, m);
    const float inv = 1.0f / sum;
    short* pb = reinterpret_cast<short*>(p);   // reads above already in registers
    #pragma unroll
    for (int j = 0; j < 16; ++j) pb[lane + j * 64] = f2h(v[j] * inv);
}

#define GLOAD_LDS(gp, lp) \
    __builtin_amdgcn_global_load_lds( \
        (const __attribute__((address_space(1))) void*)(const void*)(gp), \
        (__attribute__((address_space(3))) void*)(void*)(lp), 16, 0, 0)

// =======================================================================
// Shared GEMM core pieces (m97 structure): 128x128 tile, BK=32, 4 waves.
// =======================================================================
#define GEMM_PROLOGUE(Aptr, ldA, Bptr, ldB)                                     \
    __shared__ short As[128 * 32];                                              \
    __shared__ short Bs[128 * 32];                                              \
    const int tid  = threadIdx.x;                                               \
    const int lane = tid & 63;                                                  \
    const int wid  = tid >> 6;                                                  \
    const int wr   = wid >> 1;                                                  \
    const int wc   = wid & 1;                                                   \
    const int row0 = blockIdx.y * 128;                                          \
    const int col0 = blockIdx.x * 128;                                          \
    const int slot0 = (wid * 2 + 0) * 64 + lane;                                \
    const int slot1 = (wid * 2 + 1) * 64 + lane;                                \
    const int ar0 = slot0 >> 2, ac0 = (slot0 & 3) * 8;                          \
    const int ar1 = slot1 >> 2, ac1 = (slot1 & 3) * 8;                          \
    const short* gA0 = (Aptr) + (size_t)(row0 + ar0) * (ldA) + ac0;             \
    const short* gA1 = (Aptr) + (size_t)(row0 + ar1) * (ldA) + ac1;             \
    const short* gB0 = (Bptr) + (size_t)(col0 + ar0) * (ldB) + ac0;             \
    const short* gB1 = (Bptr) + (size_t)(col0 + ar1) * (ldB) + ac1;             \
    short* lA0 = As + (wid * 2 + 0) * 512;                                      \
    short* lA1 = As + (wid * 2 + 1) * 512;                                      \
    short* lB0 = Bs + (wid * 2 + 0) * 512;                                      \
    short* lB1 = Bs + (wid * 2 + 1) * 512;                                      \
    f32x4 acc[4][4];                                                            \
    _Pragma("unroll")                                                           \
    for (int i = 0; i < 4; ++i)                                                 \
        _Pragma("unroll")                                                       \
        for (int j = 0; j < 4; ++j)                                             \
            acc[i][j] = (f32x4){0.f, 0.f, 0.f, 0.f};                            \
    const int fragoff = (lane & 15) * 32 + (lane >> 4) * 8;

#define GEMM_KLOOP(Kdim)                                                        \
    for (int kt = 0; kt < (Kdim); kt += 32){                                    \
        __syncthreads();                                                        \
        GLOAD_LDS(gA0 + kt, lA0);                                               \
        GLOAD_LDS(gA1 + kt, lA1);                                               \
        GLOAD_LDS(gB0 + kt, lB0);                                               \
        GLOAD_LDS(gB1 + kt, lB1);                                               \
        __syncthreads();                                                        \
        f16x8 af[4], bfv[4];                                                    \
        _Pragma("unroll")                                                       \
        for (int i = 0; i < 4; ++i){                                            \
            af[i]  = *reinterpret_cast<const f16x8*>(As + (wr*64 + i*16)*32 + fragoff); \
            bfv[i] = *reinterpret_cast<const f16x8*>(Bs + (wc*64 + i*16)*32 + fragoff); \
        }                                                                       \
        _Pragma("unroll")                                                       \
        for (int mi = 0; mi < 4; ++mi)                                          \
            _Pragma("unroll")                                                   \
            for (int ni = 0; ni < 4; ++ni)                                      \
                acc[mi][ni] = __builtin_amdgcn_mfma_f32_16x16x32_f16(           \
                    af[mi], bfv[ni], acc[mi][ni], 0, 0, 0);                     \
    }

#define GEMM_NORMALIZE()                                                        \
    _Pragma("unroll")                                                           \
    for (int mi = 0; mi < 4; ++mi){                                             \
        _Pragma("unroll")                                                       \
        for (int g = 0; g < 2; ++g){                                            \
            f32x4 a0 = acc[mi][2*g], a1 = acc[mi][2*g+1];                       \
            f32x4 ss = a0*a0 + a1*a1;                                           \
            _Pragma("unroll")                                                   \
            for (int m = 1; m < 16; m <<= 1){                                   \
                ss.x += __shfl_xor(ss.x, m);                                    \
                ss.y += __shfl_xor(ss.y, m);                                    \
                ss.z += __shfl_xor(ss.z, m);                                    \
                ss.w += __shfl_xor(ss.w, m);                                    \
            }                                                                   \
            f32x4 inv;                                                          \
            inv.x = 1.0f / sqrtf(ss.x * 0.03125f + 1e-6f);                      \
            inv.y = 1.0f / sqrtf(ss.y * 0.03125f + 1e-6f);                      \
            inv.z = 1.0f / sqrtf(ss.z * 0.03125f + 1e-6f);                      \
            inv.w = 1.0f / sqrtf(ss.w * 0.03125f + 1e-6f);                      \
            acc[mi][2*g]   = a0 * inv;                                          \
            acc[mi][2*g+1] = a1 * inv;                                          \
        }                                                                       \
    }

// =======================================================================
// Fused QKV projection: z = blockIdx.z selects {0:Q(*SIG), 1:K, 2:V^T}.
// Grid (32,16,3) = 1536 blocks -> ~4 blocks/CU resident (vs 2 unfused).
// =======================================================================
__global__ __launch_bounds__(256) void versor_gemm_qkv(
    const short* __restrict__ Xf,       // A: 2048 x 4096
    const short* __restrict__ WmT3,     // B: 3 x 4096 x 4096 (q,k,v)
    short* __restrict__ Qf,
    short* __restrict__ Kf,
    short* __restrict__ Vt)
{
    const int z = blockIdx.z;
    const short* Bp = WmT3 + (size_t)z * 4096 * 4096;

    GEMM_PROLOGUE(Xf, 4096, Bp, 4096)
    GEMM_KLOOP(4096)

    const int rb = row0 + wr * 64 + (lane >> 4) * 4;   // + mi*16 + j
    const int cb = col0 + wc * 64 + (lane & 15);       // + ni*16

    GEMM_NORMALIZE()

    if (z == 0){
        // fold SIG (blade square signs) into q, then plain store
        const float sg0 = blade_sign(lane & 15, lane & 15);
        const float sg1 = blade_sign(16 | (lane & 15), 16 | (lane & 15));
        #pragma unroll
        for (int mi = 0; mi < 4; ++mi)
            #pragma unroll
            for (int ni = 0; ni < 4; ++ni){
                const f32x4 v = acc[mi][ni] * ((ni & 1) ? sg1 : sg0);
                #pragma unroll
                for (int j = 0; j < 4; ++j)
                    Qf[(size_t)(rb + mi * 16 + j) * 4096 + (cb + ni * 16)] = f2h(v[j]);
            }
    } else if (z == 1){
        #pragma unroll
        for (int mi = 0; mi < 4; ++mi)
            #pragma unroll
            for (int ni = 0; ni < 4; ++ni)
                #pragma unroll
                for (int j = 0; j < 4; ++j)
                    Kf[(size_t)(rb + mi * 16 + j) * 4096 + (cb + ni * 16)] = f2h(acc[mi][ni][j]);
    } else {
        // V^T store: (b,h,f,t), 4 consecutive t per lane
        #pragma unroll
        for (int mi = 0; mi < 4; ++mi){
            const int r = rb + mi * 16;
            const int b = r >> 10, t = r & 1023;
            #pragma unroll
            for (int ni = 0; ni < 4; ++ni){
                const int c = cb + ni * 16;
                const int h = c >> 9, f = c & 511;
                s16x4 pv;
                #pragma unroll
                for (int j = 0; j < 4; ++j) pv[j] = f2h(acc[mi][ni][j]);
                *reinterpret_cast<s16x4*>(Vt + ((size_t)((b * 8 + h) * 512 + f)) * 1024 + t) = pv;
            }
        }
    }
}

// =======================================================================
// Generic GEMM for the remaining stages.
// EPI: 3=final(f32,norm)  4=scores(torque, f32, batched)  5=PV(f16, batched)
// =======================================================================
template<int EPI>
__global__ __launch_bounds__(256) void versor_gemm(
    const short* __restrict__ Abase, int lda,
    const short* __restrict__ Bbase, int ldb,
    int K, void* __restrict__ OutP,
    const float* __restrict__ NqP, const float* __restrict__ NkP,
    const float* __restrict__ LamP)
{
    const int z = blockIdx.z;
    const short* A = Abase;
    const short* B = Bbase;
    if constexpr (EPI == 4){                       // scores: per-(b,h) slices of q,k
        const int b = z >> 3, h = z & 7;
        const size_t off = (size_t)b * 1024 * 4096 + (size_t)h * 512;
        A += off; B += off;
    }
    if constexpr (EPI == 5){                       // PV: probs + V^T slices
        A += (size_t)z * 1024 * 2048;
        B += (size_t)z * 512 * 1024;
    }

    GEMM_PROLOGUE(A, lda, B, ldb)
    GEMM_KLOOP(K)

    const int rb = row0 + wr * 64 + (lane >> 4) * 4;
    const int cb = col0 + wc * 64 + (lane & 15);

    if constexpr (EPI == 3){
        GEMM_NORMALIZE()
        float* Of = (float*)OutP;
        #pragma unroll
        for (int mi = 0; mi < 4; ++mi)
            #pragma unroll
            for (int ni = 0; ni < 4; ++ni)
                #pragma unroll
                for (int j = 0; j < 4; ++j)
                    Of[(size_t)(rb + mi * 16 + j) * 4096 + (cb + ni * 16)] = acc[mi][ni][j];
    }
    if constexpr (EPI == 4){   // scores + torque
        float* Of = (float*)OutP + (size_t)z * 1024 * 1024;
        const float lam = *LamP;
        const float* nq = NqP + z * 1024;
        const float* nk = NkP + z * 1024;
        #pragma unroll
        for (int mi = 0; mi < 4; ++mi)
            #pragma unroll
            for (int j = 0; j < 4; ++j){
                const int r = rb + mi * 16 + j;
                const float qn = nq[r];
                #pragma unroll
                for (int ni = 0; ni < 4; ++ni){
                    const int c = cb + ni * 16;
                    const float sc = acc[mi][ni][j];
                    const float tq = sqrtf(fmaxf(qn * nk[c] - sc * sc, 0.0f) + 1e-6f);
                    Of[(size_t)r * 1024 + c] = 0.25f * (sc + lam * tq);
                }
            }
    }
    if constexpr (EPI == 5){   // PV out -> attnout[(b*1024+s)*4096 + h*512 + f] f16
        short* Ob = (short*)OutP;
        const int b = z >> 3, h = z & 7;
        #pragma unroll
        for (int mi = 0; mi < 4; ++mi)
            #pragma unroll
            for (int ni = 0; ni < 4; ++ni)
                #pragma unroll
                for (int j = 0; j < 4; ++j)
                    Ob[(size_t)(b * 1024 + rb + mi * 16 + j) * 4096 + h * 512 + (cb + ni * 16)]
                        = f2h(acc[mi][ni][j]);
    }
}

// =======================================================================
extern "C" void kernel_launch(void* const* d_in, const int* in_sizes, int n_in,
                              void* d_out, int out_size, void* d_ws, size_t ws_size,
                              hipStream_t stream)
{
    (void)in_sizes; (void)n_in; (void)out_size; (void)ws_size;
    const float* x   = (const float*)d_in[0];
    const float* Wq  = (const float*)d_in[1];
    const float* Wk  = (const float*)d_in[2];
    const float* Wv  = (const float*)d_in[3];
    const float* Wo  = (const float*)d_in[4];
    const float* lam = (const float*)d_in[5];
    float* out = (float*)d_out;
    char*  ws  = (char*)d_ws;

    // workspace layout (~160.2 MB peak)
    short* Xf   = (short*)(ws);                             // 16 MB; later attn-out
    short* WmT3 = (short*)(ws + (16u  << 20));              // 96 MB (q,k,v); dead after QKV
    short* Qf   = (short*)(ws + (112u << 20));              // 16 MB
    short* Kf   = (short*)(ws + (128u << 20));              // 16 MB
    short* Vt   = (short*)(ws + (144u << 20));              // 16 MB (B,H,512,1024) f16
    float* Nq   = (float*)(ws + (160u << 20));              // 64 KB
    float* Nk   = (float*)(ws + (160u << 20) + (64u << 10));// 64 KB
    float* Sc   = (float*)(ws + (16u  << 20));              // 64 MB, overlays WmT3[0:64MB]
    short* WmTo = (short*)(ws + (80u  << 20));              // 32 MB, overlays WmT3[64:96MB]
    short* Attn = Xf;                                       // 16 MB, overlays Xf

    dim3 blk(256);
    cast_f32_f16<<<4096, blk, 0, stream>>>(x, Xf);

    dim3 gw3(8192, 3);
    build_wmat3<<<gw3, blk, 0, stream>>>(Wq, Wk, Wv, WmT3);

    dim3 gqkv(32, 16, 3);    // N=4096/128, M=2048/128, 3 projections
    versor_gemm_qkv<<<gqkv, blk, 0, stream>>>(Xf, WmT3, Qf, Kf, Vt);

    row_norms<<<4096, blk, 0, stream>>>(Qf, Kf, Nq, Nk);

    // build Wo matrix into the upper third of WmT3 region (disjoint from Sc)
    build_wmat<<<8192, blk, 0, stream>>>(Wo, WmTo);

    dim3 gsc(8, 8, 16);      // N=1024/128, M=1024/128, 16 (b,h) batches
    versor_gemm<4><<<gsc, blk, 0, stream>>>(Qf, 4096, Kf, 4096, 512, Sc, Nq, Nk, lam);
    softmax_rows<<<4096, blk, 0, stream>>>(Sc);

    dim3 gpv(4, 8, 16);      // N=512/128, M=1024/128, 16 batches
    versor_gemm<5><<<gpv, blk, 0, stream>>>((const short*)Sc, 2048, Vt, 1024, 1024, Attn,
                                            nullptr, nullptr, nullptr);

    dim3 gproj(32, 16, 1);   // N=4096/128, M=2048/128
    versor_gemm<3><<<gproj, blk, 0, stream>>>(Attn, 4096, WmTo, 4096, 4096, out,
                                              nullptr, nullptr, nullptr);
}

// Round 5
// 571.863 us; speedup vs baseline: 1.5305x; 1.0702x over previous
//
#include <hip/hip_runtime.h>
#include <stdint.h>

typedef __attribute__((ext_vector_type(4))) float    f32x4;
typedef __attribute__((ext_vector_type(8))) short    s16x8;
typedef __attribute__((ext_vector_type(4))) short    s16x4;
typedef __attribute__((ext_vector_type(8))) _Float16 f16x8;

#define DEV __device__ __forceinline__

// sign of e_a * e_b in Cl(4,1), METRIC=(1,1,1,1,-1): C[a,b,a^b]
DEV float blade_sign(int a, int b){
    int s = 0, t = a >> 1;
    while (t){ s += __popc(t & b); t >>= 1; }
    float sg = (s & 1) ? -1.0f : 1.0f;
    return ((a & b) & 16) ? -sg : sg;
}
DEV short f2h(float v){
    _Float16 h = (_Float16)v;                 // RNE f32->f16
    return __builtin_bit_cast(short, h);
}
DEV float h2f(short b){
    return (float)__builtin_bit_cast(_Float16, b);
}

// ---------------- cast x (f32) -> f16, 8 elems/thread ----------------
__global__ __launch_bounds__(256) void cast_f32_f16(const float* __restrict__ in,
                                                    short* __restrict__ out){
    const size_t idx = (size_t)blockIdx.x * 256 + threadIdx.x;
    const float4* p = reinterpret_cast<const float4*>(in) + idx * 2;
    float4 a = p[0], b = p[1];
    s16x8 o;
    o[0]=f2h(a.x); o[1]=f2h(a.y); o[2]=f2h(a.z); o[3]=f2h(a.w);
    o[4]=f2h(b.x); o[5]=f2h(b.y); o[6]=f2h(b.z); o[7]=f2h(b.w);
    *reinterpret_cast<s16x8*>(out + idx * 8) = o;
}

// ------- build WmatT f16: WmT[o*32+kb][i*32+l] = W[o,i,kb^l]*C[kb^l,l,kb] -------
DEV void build_wmat_body(const float* __restrict__ W, short* __restrict__ WmT,
                         int idx){
    const int n  = idx >> 9;          // output row (o*32+kb), 0..4095
    const int kg = idx & 511;         // 8-elem group within row
    const int o = n >> 5, kb = n & 31;
    const int i = kg >> 2, l0 = (kg & 3) * 8;
    const float* wrow = W + (size_t)(o * 128 + i) * 32;
    s16x8 v;
    #pragma unroll
    for (int e = 0; e < 8; ++e){
        const int l = l0 + e, j = kb ^ l;
        v[e] = f2h(wrow[j] * blade_sign(j, l));
    }
    *reinterpret_cast<s16x8*>(WmT + (size_t)n * 4096 + kg * 8) = v;
}

__global__ __launch_bounds__(256) void build_wmat(const float* __restrict__ W,
                                                  short* __restrict__ WmT){
    build_wmat_body(W, WmT, blockIdx.x * 256 + threadIdx.x);
}

__global__ __launch_bounds__(256) void build_wmat3(const float* __restrict__ Wq,
                                                   const float* __restrict__ Wk,
                                                   const float* __restrict__ Wv,
                                                   short* __restrict__ WmT3){
    const int w = blockIdx.y;
    const float* W = (w == 0) ? Wq : ((w == 1) ? Wk : Wv);
    build_wmat_body(W, WmT3 + (size_t)w * 4096 * 4096,
                    blockIdx.x * 256 + threadIdx.x);
}

// ---------------- per-(b,h,s) norms over 512 features (q and k) ----------------
__global__ __launch_bounds__(256) void row_norms(const short* __restrict__ Q,
                                                 const short* __restrict__ Kq,
                                                 float* __restrict__ Nq,
                                                 float* __restrict__ Nk){
    const int row  = blockIdx.x * 4 + (threadIdx.x >> 6);   // 16384 rows
    const int lane = threadIdx.x & 63;
    const int b = row >> 13, h = (row >> 10) & 7, s = row & 1023;
    const size_t off = ((size_t)(b * 1024 + s)) * 4096 + h * 512 + lane * 8;
    s16x8 a = *reinterpret_cast<const s16x8*>(Q + off);
    s16x8 c = *reinterpret_cast<const s16x8*>(Kq + off);
    float sq = 0.f, sk = 0.f;
    #pragma unroll
    for (int e = 0; e < 8; ++e){
        float fa = h2f(a[e]); sq = fmaf(fa, fa, sq);
        float fc = h2f(c[e]); sk = fmaf(fc, fc, sk);
    }
    #pragma unroll
    for (int m = 1; m < 64; m <<= 1){
        sq += __shfl_xor(sq, m);
        sk += __shfl_xor(sk, m);
    }
    if (lane == 0){ Nq[row] = sq; Nk[row] = sk; }
}

// -------- softmax per row, in place: read 1024 f32, write 1024 f16 at row head --------
__global__ __launch_bounds__(256) void softmax_rows(float* __restrict__ Sc){
    const int row  = blockIdx.x * 4 + (threadIdx.x >> 6);   // 16384 rows
    const int lane = threadIdx.x & 63;
    float* p = Sc + (size_t)row * 1024;
    float v[16];
    float mx = -3.0e38f;
    #pragma unroll
    for (int j = 0; j < 16; ++j){ v[j] = p[lane + j * 64]; mx = fmaxf(mx, v[j]); }
    #pragma unroll
    for (int m = 1; m < 64; m <<= 1) mx = fmaxf(mx, __shfl_xor(mx, m));
    float sum = 0.f;
    #pragma unroll
    for (int j = 0; j < 16; ++j){ v[j] = __expf(v[j] - mx); sum += v[j]; }
    #pragma unroll
    for (int m = 1; m < 64; m <<= 1) sum += __shfl_xor(sum, m);
    const float inv = 1.0f / sum;
    short* pb = reinterpret_cast<short*>(p);   // reads above already in registers
    #pragma unroll
    for (int j = 0; j < 16; ++j) pb[lane + j * 64] = f2h(v[j] * inv);
}

#define GLOAD_LDS(gp, lp) \
    __builtin_amdgcn_global_load_lds( \
        (const __attribute__((address_space(1))) void*)(const void*)(gp), \
        (__attribute__((address_space(3))) void*)(void*)(lp), 16, 0, 0)

// =======================================================================
// Deep-pipelined f16 MFMA GEMM ("gemm8"): 256x256 tile, BK=32, 8 waves
// (512 thr), 4-deep LDS ring (4 x 32KB = 128KB dynamic), counted vmcnt(8)
// (never 0 in the loop), 1 barrier / 32 MFMA, setprio around MFMA (T5),
// XOR bank-swizzle on LDS 16B-chunks (T2; chunk ^= (row>>1)&3, applied to
// both the pre-swizzled global_load_lds source and the ds_read address).
// Buffer ring: tile t lives in buf[t&3]; tile t+3's loads issue during
// tile t into buf[(t-1)&3], whose last reader finished before tile t's
// barrier -> no region race by construction.
// C[m][n] = sum_k A[m][k] * Bt[n][k]
// EPI: 0 = fused QKV (z from col block: 0:Q*SIG, 1:K, 2:V^T)
//      3 = final projection (norm, f32 out)
//      4 = scores (torque epilogue, f32, batched over z=(b,h))
// =======================================================================
template<int EPI>
__global__ __launch_bounds__(512, 2) void versor_gemm8(
    const short* __restrict__ Abase, int lda,
    const short* __restrict__ Bbase, int ldb,
    int K, void* __restrict__ OutP,
    const float* __restrict__ NqP, const float* __restrict__ NkP,
    const float* __restrict__ LamP,
    short* __restrict__ OQ, short* __restrict__ OK, short* __restrict__ OV)
{
    extern __shared__ short lds[];   // 4 bufs x (A 8192 | B 8192) shorts

    const int tid  = threadIdx.x;
    const int lane = tid & 63;
    const int wid  = tid >> 6;        // 0..7
    const int wm   = wid >> 2;        // 0..1  (row half of C)
    const int wn   = wid & 3;         // 0..3  (col quarter of C)
    const int z    = blockIdx.z;

    const short* A = Abase;
    const short* B = Bbase;
    if constexpr (EPI == 4){          // scores: per-(b,h) slices of q,k
        const int b = z >> 3, h = z & 7;
        const size_t off = (size_t)b * 1024 * 4096 + (size_t)h * 512;
        A += off; B += off;
    }
    const int row0 = blockIdx.y * 256;
    const int col0 = blockIdx.x * 256;

    // ---- staging (global -> LDS), per-wave 2 A-chunks + 2 B-chunks / tile ----
    // LDS chunk C (16 rows x 32 shorts = 1KB): lane l writes bytes C*1024+l*16
    //   -> (row = C*16 + (l>>2), slot = l&3). Slot holds logical k-chunk
    //   j = slot ^ ((row>>1)&3) = (l&3) ^ ((l>>3)&3)  [pre-swizzled source].
    const int jsw = ((lane & 3) ^ ((lane >> 3) & 3)) * 8;      // shorts
    const short* gA0 = A + (size_t)(row0 + wid * 32 + (lane >> 2)) * lda + jsw;
    const short* gA1 = gA0 + (size_t)16 * lda;
    const short* gB0 = B + (size_t)(col0 + wid * 32 + (lane >> 2)) * ldb + jsw;
    const short* gB1 = gB0 + (size_t)16 * ldb;
    const int dA0 = wid * 1024, dA1 = dA0 + 512;               // shorts
    const int dB0 = 8192 + wid * 1024, dB1 = dB0 + 512;

    // ---- ds_read fragment bases (swizzled): frag (row r, k-chunk i) at
    //      r*32 + (i ^ ((r>>1)&3))*8; with r = 16*m + (lane&15), i = lane>>4
    //      the XOR term is lane-only.
    const int swz = ((lane >> 4) ^ (((lane & 15) >> 1) & 3)) * 8;
    const int ard = (wm * 128 + (lane & 15)) * 32 + swz;        // + mi*512
    const int brd = 8192 + (wn * 64 + (lane & 15)) * 32 + swz;  // + ni*512

    f32x4 acc[8][4];
    #pragma unroll
    for (int i = 0; i < 8; ++i)
        #pragma unroll
        for (int j = 0; j < 4; ++j)
            acc[i][j] = (f32x4){0.f, 0.f, 0.f, 0.f};

    const int NT = K >> 5;            // K-tiles of 32 (NT >= 16 for all uses)

    // prologue: stage tiles 0,1,2 into ring slots 0,1,2
    #pragma unroll
    for (int pt = 0; pt < 3; ++pt){
        const int bb = pt * 16384;
        GLOAD_LDS(gA0 + pt * 32, lds + bb + dA0);
        GLOAD_LDS(gA1 + pt * 32, lds + bb + dA1);
        GLOAD_LDS(gB0 + pt * 32, lds + bb + dB0);
        GLOAD_LDS(gB1 + pt * 32, lds + bb + dB1);
    }

    for (int t = 0; t < NT; ++t){
        const int bb = (t & 3) * 16384;
        // own tile-t loads are >= 8 older than anything newer (2 tiles x 4)
        asm volatile("s_waitcnt vmcnt(8)" ::: "memory");
        __builtin_amdgcn_s_barrier();       // everyone's tile-t loads landed
        asm volatile("" ::: "memory");
        __builtin_amdgcn_sched_barrier(0);  // pin: no ds_read above this line

        if (t + 3 < NT){                    // stage A of tile t+3 (free slot)
            const int nb = ((t + 3) & 3) * 16384;
            GLOAD_LDS(gA0 + (t + 3) * 32, lds + nb + dA0);
            GLOAD_LDS(gA1 + (t + 3) * 32, lds + nb + dA1);
        }
        f16x8 av[4], bv[4];
        #pragma unroll
        for (int i = 0; i < 4; ++i){
            av[i] = *reinterpret_cast<const f16x8*>(lds + bb + ard + i * 512);
            bv[i] = *reinterpret_cast<const f16x8*>(lds + bb + brd + i * 512);
        }
        __builtin_amdgcn_s_setprio(1);
        #pragma unroll
        for (int mi = 0; mi < 4; ++mi)
            #pragma unroll
            for (int ni = 0; ni < 4; ++ni)
                acc[mi][ni] = __builtin_amdgcn_mfma_f32_16x16x32_f16(
                    av[mi], bv[ni], acc[mi][ni], 0, 0, 0);
        __builtin_amdgcn_s_setprio(0);

        if (t + 3 < NT){                    // stage B of tile t+3
            const int nb = ((t + 3) & 3) * 16384;
            GLOAD_LDS(gB0 + (t + 3) * 32, lds + nb + dB0);
            GLOAD_LDS(gB1 + (t + 3) * 32, lds + nb + dB1);
        }
        f16x8 aw[4];
        #pragma unroll
        for (int i = 0; i < 4; ++i)
            aw[i] = *reinterpret_cast<const f16x8*>(lds + bb + ard + (4 + i) * 512);
        __builtin_amdgcn_s_setprio(1);
        #pragma unroll
        for (int mi = 0; mi < 4; ++mi)
            #pragma unroll
            for (int ni = 0; ni < 4; ++ni)
                acc[4 + mi][ni] = __builtin_amdgcn_mfma_f32_16x16x32_f16(
                    aw[mi], bv[ni], acc[4 + mi][ni], 0, 0, 0);
        __builtin_amdgcn_s_setprio(0);
    }

    // ---------------- epilogue ----------------
    const int rb = row0 + wm * 128 + (lane >> 4) * 4;   // + mi*16 + j
    const int cb = col0 + wn * 64 + (lane & 15);        // + ni*16

    if constexpr (EPI == 0 || EPI == 3){
        // normalize each 32-col blade group to unit RMS
        #pragma unroll
        for (int mi = 0; mi < 8; ++mi){
            #pragma unroll
            for (int g = 0; g < 2; ++g){
                f32x4 a0 = acc[mi][2 * g], a1 = acc[mi][2 * g + 1];
                f32x4 ss = a0 * a0 + a1 * a1;
                #pragma unroll
                for (int m = 1; m < 16; m <<= 1){
                    ss.x += __shfl_xor(ss.x, m);
                    ss.y += __shfl_xor(ss.y, m);
                    ss.z += __shfl_xor(ss.z, m);
                    ss.w += __shfl_xor(ss.w, m);
                }
                f32x4 inv;
                inv.x = 1.0f / sqrtf(ss.x * 0.03125f + 1e-6f);
                inv.y = 1.0f / sqrtf(ss.y * 0.03125f + 1e-6f);
                inv.z = 1.0f / sqrtf(ss.z * 0.03125f + 1e-6f);
                inv.w = 1.0f / sqrtf(ss.w * 0.03125f + 1e-6f);
                acc[mi][2 * g]     = a0 * inv;
                acc[mi][2 * g + 1] = a1 * inv;
            }
        }
    }

    if constexpr (EPI == 0){
        const int zsel = col0 >> 12;          // 0:Q 1:K 2:V
        const int cbm  = (col0 & 4095) + wn * 64 + (lane & 15);
        if (zsel == 0){
            const float sg0 = blade_sign(lane & 15, lane & 15);
            const float sg1 = blade_sign(16 | (lane & 15), 16 | (lane & 15));
            #pragma unroll
            for (int mi = 0; mi < 8; ++mi)
                #pragma unroll
                for (int ni = 0; ni < 4; ++ni){
                    const f32x4 v = acc[mi][ni] * ((ni & 1) ? sg1 : sg0);
                    #pragma unroll
                    for (int j = 0; j < 4; ++j)
                        OQ[(size_t)(rb + mi * 16 + j) * 4096 + (cbm + ni * 16)] = f2h(v[j]);
                }
        } else if (zsel == 1){
            #pragma unroll
            for (int mi = 0; mi < 8; ++mi)
                #pragma unroll
                for (int ni = 0; ni < 4; ++ni)
                    #pragma unroll
                    for (int j = 0; j < 4; ++j)
                        OK[(size_t)(rb + mi * 16 + j) * 4096 + (cbm + ni * 16)] = f2h(acc[mi][ni][j]);
        } else {
            // V^T store: (b,h,f,t), 4 consecutive t per lane
            #pragma unroll
            for (int mi = 0; mi < 8; ++mi){
                const int r = rb + mi * 16;
                const int b = r >> 10, tt = r & 1023;
                #pragma unroll
                for (int ni = 0; ni < 4; ++ni){
                    const int c = cbm + ni * 16;
                    const int h = c >> 9, f = c & 511;
                    s16x4 pv;
                    #pragma unroll
                    for (int j = 0; j < 4; ++j) pv[j] = f2h(acc[mi][ni][j]);
                    *reinterpret_cast<s16x4*>(OV + ((size_t)((b * 8 + h) * 512 + f)) * 1024 + tt) = pv;
                }
            }
        }
    }
    if constexpr (EPI == 3){
        float* Of = (float*)OutP;
        #pragma unroll
        for (int mi = 0; mi < 8; ++mi)
            #pragma unroll
            for (int ni = 0; ni < 4; ++ni)
                #pragma unroll
                for (int j = 0; j < 4; ++j)
                    Of[(size_t)(rb + mi * 16 + j) * 4096 + (cb + ni * 16)] = acc[mi][ni][j];
    }
    if constexpr (EPI == 4){   // scores + torque
        float* Of = (float*)OutP + (size_t)z * 1024 * 1024;
        const float lam = *LamP;
        const float* nq = NqP + z * 1024;
        const float* nk = NkP + z * 1024;
        #pragma unroll
        for (int mi = 0; mi < 8; ++mi)
            #pragma unroll
            for (int j = 0; j < 4; ++j){
                const int r = rb + mi * 16 + j;
                const float qn = nq[r];
                #pragma unroll
                for (int ni = 0; ni < 4; ++ni){
                    const int c = cb + ni * 16;
                    const float sc = acc[mi][ni][j];
                    const float tq = sqrtf(fmaxf(qn * nk[c] - sc * sc, 0.0f) + 1e-6f);
                    Of[(size_t)r * 1024 + c] = 0.25f * (sc + lam * tq);
                }
            }
    }
}

// =======================================================================
// Old 2-phase 128x128 kernel, kept for PV (small K, many blocks).
// =======================================================================
__global__ __launch_bounds__(256) void versor_gemm_pv(
    const short* __restrict__ Abase, int lda,
    const short* __restrict__ Bbase, int ldb,
    int K, short* __restrict__ OutP)
{
    __shared__ short As[128 * 32];
    __shared__ short Bs[128 * 32];

    const int tid  = threadIdx.x;
    const int lane = tid & 63;
    const int wid  = tid >> 6;
    const int wr   = wid >> 1;
    const int wc   = wid & 1;
    const int z    = blockIdx.z;

    const short* A = Abase + (size_t)z * 1024 * 2048;
    const short* B = Bbase + (size_t)z * 512 * 1024;

    const int row0 = blockIdx.y * 128;
    const int col0 = blockIdx.x * 128;

    const int slot0 = (wid * 2 + 0) * 64 + lane;
    const int slot1 = (wid * 2 + 1) * 64 + lane;
    const int ar0 = slot0 >> 2, ac0 = (slot0 & 3) * 8;
    const int ar1 = slot1 >> 2, ac1 = (slot1 & 3) * 8;
    const short* gA0 = A + (size_t)(row0 + ar0) * lda + ac0;
    const short* gA1 = A + (size_t)(row0 + ar1) * lda + ac1;
    const short* gB0 = B + (size_t)(col0 + ar0) * ldb + ac0;
    const short* gB1 = B + (size_t)(col0 + ar1) * ldb + ac1;
    short* lA0 = As + (wid * 2 + 0) * 512;
    short* lA1 = As + (wid * 2 + 1) * 512;
    short* lB0 = Bs + (wid * 2 + 0) * 512;
    short* lB1 = Bs + (wid * 2 + 1) * 512;

    f32x4 acc[4][4];
    #pragma unroll
    for (int i = 0; i < 4; ++i)
        #pragma unroll
        for (int j = 0; j < 4; ++j)
            acc[i][j] = (f32x4){0.f, 0.f, 0.f, 0.f};

    const int fragoff = (lane & 15) * 32 + (lane >> 4) * 8;

    for (int kt = 0; kt < K; kt += 32){
        __syncthreads();
        GLOAD_LDS(gA0 + kt, lA0);
        GLOAD_LDS(gA1 + kt, lA1);
        GLOAD_LDS(gB0 + kt, lB0);
        GLOAD_LDS(gB1 + kt, lB1);
        __syncthreads();

        f16x8 af[4], bfv[4];
        #pragma unroll
        for (int i = 0; i < 4; ++i){
            af[i]  = *reinterpret_cast<const f16x8*>(As + (wr * 64 + i * 16) * 32 + fragoff);
            bfv[i] = *reinterpret_cast<const f16x8*>(Bs + (wc * 64 + i * 16) * 32 + fragoff);
        }
        #pragma unroll
        for (int mi = 0; mi < 4; ++mi)
            #pragma unroll
            for (int ni = 0; ni < 4; ++ni)
                acc[mi][ni] = __builtin_amdgcn_mfma_f32_16x16x32_f16(
                    af[mi], bfv[ni], acc[mi][ni], 0, 0, 0);
    }

    const int rb = row0 + wr * 64 + (lane >> 4) * 4;
    const int cb = col0 + wc * 64 + (lane & 15);
    const int b = z >> 3, h = z & 7;
    #pragma unroll
    for (int mi = 0; mi < 4; ++mi)
        #pragma unroll
        for (int ni = 0; ni < 4; ++ni)
            #pragma unroll
            for (int j = 0; j < 4; ++j)
                OutP[(size_t)(b * 1024 + rb + mi * 16 + j) * 4096 + h * 512 + (cb + ni * 16)]
                    = f2h(acc[mi][ni][j]);
}

// =======================================================================
extern "C" void kernel_launch(void* const* d_in, const int* in_sizes, int n_in,
                              void* d_out, int out_size, void* d_ws, size_t ws_size,
                              hipStream_t stream)
{
    (void)in_sizes; (void)n_in; (void)out_size; (void)ws_size;
    const float* x   = (const float*)d_in[0];
    const float* Wq  = (const float*)d_in[1];
    const float* Wk  = (const float*)d_in[2];
    const float* Wv  = (const float*)d_in[3];
    const float* Wo  = (const float*)d_in[4];
    const float* lam = (const float*)d_in[5];
    float* out = (float*)d_out;
    char*  ws  = (char*)d_ws;

    // workspace layout (~160.2 MB peak)
    short* Xf   = (short*)(ws);                             // 16 MB; later attn-out
    short* WmT3 = (short*)(ws + (16u  << 20));              // 96 MB (q,k,v); dead after QKV
    short* Qf   = (short*)(ws + (112u << 20));              // 16 MB
    short* Kf   = (short*)(ws + (128u << 20));              // 16 MB
    short* Vt   = (short*)(ws + (144u << 20));              // 16 MB (B,H,512,1024) f16
    float* Nq   = (float*)(ws + (160u << 20));              // 64 KB
    float* Nk   = (float*)(ws + (160u << 20) + (64u << 10));// 64 KB
    float* Sc   = (float*)(ws + (16u  << 20));              // 64 MB, overlays WmT3[0:64MB]
    short* WmTo = (short*)(ws + (80u  << 20));              // 32 MB, overlays WmT3[64:96MB]
    short* Attn = Xf;                                       // 16 MB, overlays Xf

    const int DYN_LDS = 131072;
    hipFuncSetAttribute(reinterpret_cast<const void*>(versor_gemm8<0>),
                        hipFuncAttributeMaxDynamicSharedMemorySize, DYN_LDS);
    hipFuncSetAttribute(reinterpret_cast<const void*>(versor_gemm8<3>),
                        hipFuncAttributeMaxDynamicSharedMemorySize, DYN_LDS);
    hipFuncSetAttribute(reinterpret_cast<const void*>(versor_gemm8<4>),
                        hipFuncAttributeMaxDynamicSharedMemorySize, DYN_LDS);

    dim3 blk(256), blk8(512);
    cast_f32_f16<<<4096, blk, 0, stream>>>(x, Xf);

    dim3 gw3(8192, 3);
    build_wmat3<<<gw3, blk, 0, stream>>>(Wq, Wk, Wv, WmT3);

    // fused QKV: A=Xf (2048x4096), B=WmT3 as one (12288x4096) stack
    dim3 gqkv(48, 8, 1);
    versor_gemm8<0><<<gqkv, blk8, DYN_LDS, stream>>>(
        Xf, 4096, WmT3, 4096, 4096, nullptr, nullptr, nullptr, nullptr, Qf, Kf, Vt);

    row_norms<<<4096, blk, 0, stream>>>(Qf, Kf, Nq, Nk);

    // build Wo matrix into the upper third of the WmT3 region (disjoint from Sc)
    build_wmat<<<8192, blk, 0, stream>>>(Wo, WmTo);

    dim3 gsc(4, 4, 16);      // 1024/256 x 1024/256 x 16 (b,h)
    versor_gemm8<4><<<gsc, blk8, DYN_LDS, stream>>>(
        Qf, 4096, Kf, 4096, 512, Sc, Nq, Nk, lam, nullptr, nullptr, nullptr);
    softmax_rows<<<4096, blk, 0, stream>>>(Sc);

    dim3 gpv(4, 8, 16);      // N=512/128, M=1024/128, 16 batches (old 2-phase)
    versor_gemm_pv<<<gpv, blk, 0, stream>>>((const short*)Sc, 2048, Vt, 1024, 1024, Attn);

    dim3 gfin(16, 8, 1);     // N=4096/256, M=2048/256
    versor_gemm8<3><<<gfin, blk8, DYN_LDS, stream>>>(
        Attn, 4096, WmTo, 4096, 4096, out, nullptr, nullptr, nullptr, nullptr, nullptr, nullptr);
}

// Round 6
// 553.706 us; speedup vs baseline: 1.5807x; 1.0328x over previous
//
#include <hip/hip_runtime.h>
#include <stdint.h>

typedef __attribute__((ext_vector_type(4))) float    f32x4;
typedef __attribute__((ext_vector_type(8))) short    s16x8;
typedef __attribute__((ext_vector_type(4))) short    s16x4;
typedef __attribute__((ext_vector_type(8))) _Float16 f16x8;

#define DEV __device__ __forceinline__

// sign of e_a * e_b in Cl(4,1), METRIC=(1,1,1,1,-1): C[a,b,a^b]
DEV float blade_sign(int a, int b){
    int s = 0, t = a >> 1;
    while (t){ s += __popc(t & b); t >>= 1; }
    float sg = (s & 1) ? -1.0f : 1.0f;
    return ((a & b) & 16) ? -sg : sg;
}
DEV short f2h(float v){
    _Float16 h = (_Float16)v;                 // RNE f32->f16
    return __builtin_bit_cast(short, h);
}
DEV float h2f(short b){
    return (float)__builtin_bit_cast(_Float16, b);
}
DEV void wait_vm(int n){                      // literal-arg folded vmcnt
    if (n == 8)      asm volatile("s_waitcnt vmcnt(8)" ::: "memory");
    else if (n == 4) asm volatile("s_waitcnt vmcnt(4)" ::: "memory");
    else             asm volatile("s_waitcnt vmcnt(0)" ::: "memory");
}

// ---------------- cast x (f32) -> f16, 8 elems/thread ----------------
__global__ __launch_bounds__(256) void cast_f32_f16(const float* __restrict__ in,
                                                    short* __restrict__ out){
    const size_t idx = (size_t)blockIdx.x * 256 + threadIdx.x;
    const float4* p = reinterpret_cast<const float4*>(in) + idx * 2;
    float4 a = p[0], b = p[1];
    s16x8 o;
    o[0]=f2h(a.x); o[1]=f2h(a.y); o[2]=f2h(a.z); o[3]=f2h(a.w);
    o[4]=f2h(b.x); o[5]=f2h(b.y); o[6]=f2h(b.z); o[7]=f2h(b.w);
    *reinterpret_cast<s16x8*>(out + idx * 8) = o;
}

// ------- build WmatT f16: WmT[o*32+kb][i*32+l] = W[o,i,kb^l]*C[kb^l,l,kb] -------
DEV void build_wmat_body(const float* __restrict__ W, short* __restrict__ WmT,
                         int idx){
    const int n  = idx >> 9;
    const int kg = idx & 511;
    const int o = n >> 5, kb = n & 31;
    const int i = kg >> 2, l0 = (kg & 3) * 8;
    const float* wrow = W + (size_t)(o * 128 + i) * 32;
    s16x8 v;
    #pragma unroll
    for (int e = 0; e < 8; ++e){
        const int l = l0 + e, j = kb ^ l;
        v[e] = f2h(wrow[j] * blade_sign(j, l));
    }
    *reinterpret_cast<s16x8*>(WmT + (size_t)n * 4096 + kg * 8) = v;
}

__global__ __launch_bounds__(256) void build_wmat(const float* __restrict__ W,
                                                  short* __restrict__ WmT){
    build_wmat_body(W, WmT, blockIdx.x * 256 + threadIdx.x);
}

__global__ __launch_bounds__(256) void build_wmat3(const float* __restrict__ Wq,
                                                   const float* __restrict__ Wk,
                                                   const float* __restrict__ Wv,
                                                   short* __restrict__ WmT3){
    const int w = blockIdx.y;
    const float* W = (w == 0) ? Wq : ((w == 1) ? Wk : Wv);
    build_wmat_body(W, WmT3 + (size_t)w * 4096 * 4096,
                    blockIdx.x * 256 + threadIdx.x);
}

// ---------------- per-(b,h,s) norms over 512 features (q and k) ----------------
__global__ __launch_bounds__(256) void row_norms(const short* __restrict__ Q,
                                                 const short* __restrict__ Kq,
                                                 float* __restrict__ Nq,
                                                 float* __restrict__ Nk){
    const int row  = blockIdx.x * 4 + (threadIdx.x >> 6);
    const int lane = threadIdx.x & 63;
    const int b = row >> 13, h = (row >> 10) & 7, s = row & 1023;
    const size_t off = ((size_t)(b * 1024 + s)) * 4096 + h * 512 + lane * 8;
    s16x8 a = *reinterpret_cast<const s16x8*>(Q + off);
    s16x8 c = *reinterpret_cast<const s16x8*>(Kq + off);
    float sq = 0.f, sk = 0.f;
    #pragma unroll
    for (int e = 0; e < 8; ++e){
        float fa = h2f(a[e]); sq = fmaf(fa, fa, sq);
        float fc = h2f(c[e]); sk = fmaf(fc, fc, sk);
    }
    #pragma unroll
    for (int m = 1; m < 64; m <<= 1){
        sq += __shfl_xor(sq, m);
        sk += __shfl_xor(sk, m);
    }
    if (lane == 0){ Nq[row] = sq; Nk[row] = sk; }
}

// -------- softmax per row, in place: read 1024 f32, write 1024 f16 at row head --------
__global__ __launch_bounds__(256) void softmax_rows(float* __restrict__ Sc){
    const int row  = blockIdx.x * 4 + (threadIdx.x >> 6);
    const int lane = threadIdx.x & 63;
    float* p = Sc + (size_t)row * 1024;
    float v[16];
    float mx = -3.0e38f;
    #pragma unroll
    for (int j = 0; j < 16; ++j){ v[j] = p[lane + j * 64]; mx = fmaxf(mx, v[j]); }
    #pragma unroll
    for (int m = 1; m < 64; m <<= 1) mx = fmaxf(mx, __shfl_xor(mx, m));
    float sum = 0.f;
    #pragma unroll
    for (int j = 0; j < 16; ++j){ v[j] = __expf(v[j] - mx); sum += v[j]; }
    #pragma unroll
    for (int m = 1; m < 64; m <<= 1) sum += __shfl_xor(sum, m);
    const float inv = 1.0f / sum;
    short* pb = reinterpret_cast<short*>(p);
    #pragma unroll
    for (int j = 0; j < 16; ++j) pb[lane + j * 64] = f2h(v[j] * inv);
}

#define GLOAD_LDS(gp, lp) \
    __builtin_amdgcn_global_load_lds( \
        (const __attribute__((address_space(1))) void*)(const void*)(gp), \
        (__attribute__((address_space(3))) void*)(void*)(lp), 16, 0, 0)

// =======================================================================
// 128x128 ring-3 pipelined GEMM: BK=32, 4 waves (2x2, 64x64/wave),
// 48 KB static LDS -> 3 blocks/CU (12 waves/CU). Counted vmcnt(4) in the
// main loop, peeled last tile with vmcnt(0) (derived waits, no race).
// XOR swizzle on 16B chunks (conflict-free, verified R5). setprio on MFMA.
// C[m][n] = sum_k A[m][k] * Bt[n][k]
// EPI: 0 = fused QKV (col0>>12 selects Q*SIG / K / V^T)
//      3 = final (norm, f32)    5 = PV (f16, batched over z)
// =======================================================================
#define R3_TILE(T, WN, PF)                                                      \
  {                                                                             \
    const int bb = cur * 8192;                                                  \
    wait_vm(WN);                                                                \
    __builtin_amdgcn_s_barrier();                                               \
    asm volatile("" ::: "memory");                                              \
    __builtin_amdgcn_sched_barrier(0);                                          \
    const int sb = stg * 8192;                                                  \
    if (PF){                                                                    \
        GLOAD_LDS(gA0 + (size_t)((T) + 2) * 32, lds + sb + dA0);                \
        GLOAD_LDS(gA1 + (size_t)((T) + 2) * 32, lds + sb + dA1);                \
    }                                                                           \
    f16x8 av[4], bv[4];                                                         \
    _Pragma("unroll")                                                           \
    for (int i = 0; i < 4; ++i)                                                 \
        av[i] = *reinterpret_cast<const f16x8*>(lds + bb + ard + i * 512);      \
    bv[0] = *reinterpret_cast<const f16x8*>(lds + bb + brd + 0 * 512);          \
    bv[1] = *reinterpret_cast<const f16x8*>(lds + bb + brd + 1 * 512);          \
    __builtin_amdgcn_s_setprio(1);                                              \
    _Pragma("unroll")                                                           \
    for (int mi = 0; mi < 4; ++mi)                                              \
        _Pragma("unroll")                                                       \
        for (int ni = 0; ni < 2; ++ni)                                          \
            acc[mi][ni] = __builtin_amdgcn_mfma_f32_16x16x32_f16(               \
                av[mi], bv[ni], acc[mi][ni], 0, 0, 0);                          \
    __builtin_amdgcn_s_setprio(0);                                              \
    if (PF){                                                                    \
        GLOAD_LDS(gB0 + (size_t)((T) + 2) * 32, lds + sb + dB0);                \
        GLOAD_LDS(gB1 + (size_t)((T) + 2) * 32, lds + sb + dB1);                \
    }                                                                           \
    bv[2] = *reinterpret_cast<const f16x8*>(lds + bb + brd + 2 * 512);          \
    bv[3] = *reinterpret_cast<const f16x8*>(lds + bb + brd + 3 * 512);          \
    __builtin_amdgcn_s_setprio(1);                                              \
    _Pragma("unroll")                                                           \
    for (int mi = 0; mi < 4; ++mi)                                              \
        _Pragma("unroll")                                                       \
        for (int ni = 2; ni < 4; ++ni)                                          \
            acc[mi][ni] = __builtin_amdgcn_mfma_f32_16x16x32_f16(               \
                av[mi], bv[ni], acc[mi][ni], 0, 0, 0);                          \
    __builtin_amdgcn_s_setprio(0);                                              \
    cur = (cur == 2) ? 0 : cur + 1;                                             \
    stg = (stg == 2) ? 0 : stg + 1;                                             \
  }

template<int EPI>
__global__ __launch_bounds__(256, 3) void versor_gemm_r3(
    const short* __restrict__ Abase, int lda,
    const short* __restrict__ Bbase, int ldb,
    int K, void* __restrict__ OutP,
    short* __restrict__ OQ, short* __restrict__ OK, short* __restrict__ OV)
{
    __shared__ short lds[3 * 8192];   // 3 bufs x (A 128x32 | B 128x32)

    const int tid  = threadIdx.x;
    const int lane = tid & 63;
    const int wid  = tid >> 6;        // 0..3
    const int wr   = wid >> 1;
    const int wc   = wid & 1;
    const int z    = blockIdx.z;

    const short* A = Abase;
    const short* B = Bbase;
    if constexpr (EPI == 5){          // PV: probs + V^T slices
        A += (size_t)z * 1024 * 2048;
        B += (size_t)z * 512 * 1024;
    }
    const int row0 = blockIdx.y * 128;
    const int col0 = blockIdx.x * 128;

    // staging: chunk (r*256 + wid*64 + lane) -> LDS shorts (r*2048 + wid*512 + lane*8)
    // local row = r*64 + wid*16 + (lane>>2); swizzled k-chunk = (lane&3)^((lane>>3)&3)
    const int jsw = ((lane & 3) ^ ((lane >> 3) & 3)) * 8;
    const short* gA0 = A + (size_t)(row0 + wid * 16 + (lane >> 2)) * lda + jsw;
    const short* gA1 = gA0 + (size_t)64 * lda;
    const short* gB0 = B + (size_t)(col0 + wid * 16 + (lane >> 2)) * ldb + jsw;
    const short* gB1 = gB0 + (size_t)64 * ldb;
    const int dA0 = wid * 512,        dA1 = 2048 + wid * 512;
    const int dB0 = 4096 + wid * 512, dB1 = 6144 + wid * 512;

    // ds_read frag bases (swizzled, lane-only XOR)
    const int swz = ((lane >> 4) ^ (((lane & 15) >> 1) & 3)) * 8;
    const int ard = (wr * 64 + (lane & 15)) * 32 + swz;          // + mi*512
    const int brd = 4096 + (wc * 64 + (lane & 15)) * 32 + swz;   // + ni*512

    f32x4 acc[4][4];
    #pragma unroll
    for (int i = 0; i < 4; ++i)
        #pragma unroll
        for (int j = 0; j < 4; ++j)
            acc[i][j] = (f32x4){0.f, 0.f, 0.f, 0.f};

    const int NT = K >> 5;

    // prologue: stage tiles 0,1 into slots 0,1
    #pragma unroll
    for (int pt = 0; pt < 2; ++pt){
        const int sb = pt * 8192;
        GLOAD_LDS(gA0 + pt * 32, lds + sb + dA0);
        GLOAD_LDS(gA1 + pt * 32, lds + sb + dA1);
        GLOAD_LDS(gB0 + pt * 32, lds + sb + dB0);
        GLOAD_LDS(gB1 + pt * 32, lds + sb + dB1);
    }

    int cur = 0, stg = 2;
    for (int t = 0; t < NT - 1; ++t)
        R3_TILE(t, 4, (t + 2 < NT))
    R3_TILE(NT - 1, 0, false)

    // ---------------- epilogue ----------------
    const int rb = row0 + wr * 64 + (lane >> 4) * 4;   // + mi*16 + j
    const int cb = col0 + wc * 64 + (lane & 15);       // + ni*16

    if constexpr (EPI == 0 || EPI == 3){
        // normalize each 32-col blade group to unit RMS
        #pragma unroll
        for (int mi = 0; mi < 4; ++mi){
            #pragma unroll
            for (int g = 0; g < 2; ++g){
                f32x4 a0 = acc[mi][2 * g], a1 = acc[mi][2 * g + 1];
                f32x4 ss = a0 * a0 + a1 * a1;
                #pragma unroll
                for (int m = 1; m < 16; m <<= 1){
                    ss.x += __shfl_xor(ss.x, m);
                    ss.y += __shfl_xor(ss.y, m);
                    ss.z += __shfl_xor(ss.z, m);
                    ss.w += __shfl_xor(ss.w, m);
                }
                f32x4 inv;
                inv.x = 1.0f / sqrtf(ss.x * 0.03125f + 1e-6f);
                inv.y = 1.0f / sqrtf(ss.y * 0.03125f + 1e-6f);
                inv.z = 1.0f / sqrtf(ss.z * 0.03125f + 1e-6f);
                inv.w = 1.0f / sqrtf(ss.w * 0.03125f + 1e-6f);
                acc[mi][2 * g]     = a0 * inv;
                acc[mi][2 * g + 1] = a1 * inv;
            }
        }
    }

    if constexpr (EPI == 0){
        const int zsel = col0 >> 12;          // 0:Q 1:K 2:V
        const int cbm  = (col0 & 4095) + wc * 64 + (lane & 15);
        if (zsel == 0){
            const float sg0 = blade_sign(lane & 15, lane & 15);
            const float sg1 = blade_sign(16 | (lane & 15), 16 | (lane & 15));
            #pragma unroll
            for (int mi = 0; mi < 4; ++mi)
                #pragma unroll
                for (int ni = 0; ni < 4; ++ni){
                    const f32x4 v = acc[mi][ni] * ((ni & 1) ? sg1 : sg0);
                    #pragma unroll
                    for (int j = 0; j < 4; ++j)
                        OQ[(size_t)(rb + mi * 16 + j) * 4096 + (cbm + ni * 16)] = f2h(v[j]);
                }
        } else if (zsel == 1){
            #pragma unroll
            for (int mi = 0; mi < 4; ++mi)
                #pragma unroll
                for (int ni = 0; ni < 4; ++ni)
                    #pragma unroll
                    for (int j = 0; j < 4; ++j)
                        OK[(size_t)(rb + mi * 16 + j) * 4096 + (cbm + ni * 16)] = f2h(acc[mi][ni][j]);
        } else {
            // V^T store: (b,h,f,t), 4 consecutive t per lane
            #pragma unroll
            for (int mi = 0; mi < 4; ++mi){
                const int r = rb + mi * 16;
                const int b = r >> 10, tt = r & 1023;
                #pragma unroll
                for (int ni = 0; ni < 4; ++ni){
                    const int c = cbm + ni * 16;
                    const int h = c >> 9, f = c & 511;
                    s16x4 pv;
                    #pragma unroll
                    for (int j = 0; j < 4; ++j) pv[j] = f2h(acc[mi][ni][j]);
                    *reinterpret_cast<s16x4*>(OV + ((size_t)((b * 8 + h) * 512 + f)) * 1024 + tt) = pv;
                }
            }
        }
    }
    if constexpr (EPI == 3){
        float* Of = (float*)OutP;
        #pragma unroll
        for (int mi = 0; mi < 4; ++mi)
            #pragma unroll
            for (int ni = 0; ni < 4; ++ni)
                #pragma unroll
                for (int j = 0; j < 4; ++j)
                    Of[(size_t)(rb + mi * 16 + j) * 4096 + (cb + ni * 16)] = acc[mi][ni][j];
    }
    if constexpr (EPI == 5){   // PV out -> attnout[(b*1024+s)*4096 + h*512 + f] f16
        short* Ob = (short*)OutP;
        const int b = z >> 3, h = z & 7;
        #pragma unroll
        for (int mi = 0; mi < 4; ++mi)
            #pragma unroll
            for (int ni = 0; ni < 4; ++ni)
                #pragma unroll
                for (int j = 0; j < 4; ++j)
                    Ob[(size_t)(b * 1024 + rb + mi * 16 + j) * 4096 + h * 512 + (cb + ni * 16)]
                        = f2h(acc[mi][ni][j]);
    }
}

// =======================================================================
// Scores kernel (256x256, 8 waves, ring-4, dyn 128KB LDS) with torque
// epilogue. Peeled tail (vmcnt 8 -> 4 -> 0) fixes the R5 latent race.
// =======================================================================
#define SC_TILE(T, WN, PF)                                                      \
  {                                                                             \
    const int bb = ((T) & 3) * 16384;                                           \
    wait_vm(WN);                                                                \
    __builtin_amdgcn_s_barrier();                                               \
    asm volatile("" ::: "memory");                                              \
    __builtin_amdgcn_sched_barrier(0);                                          \
    if (PF){                                                                    \
        const int nb = (((T) + 3) & 3) * 16384;                                 \
        GLOAD_LDS(gA0 + (size_t)((T) + 3) * 32, lds + nb + dA0);                \
        GLOAD_LDS(gA1 + (size_t)((T) + 3) * 32, lds + nb + dA1);                \
    }                                                                           \
    f16x8 av[4], bv[4];                                                         \
    _Pragma("unroll")                                                           \
    for (int i = 0; i < 4; ++i){                                                \
        av[i] = *reinterpret_cast<const f16x8*>(lds + bb + ard + i * 512);      \
        bv[i] = *reinterpret_cast<const f16x8*>(lds + bb + brd + i * 512);      \
    }                                                                           \
    __builtin_amdgcn_s_setprio(1);                                              \
    _Pragma("unroll")                                                           \
    for (int mi = 0; mi < 4; ++mi)                                              \
        _Pragma("unroll")                                                       \
        for (int ni = 0; ni < 4; ++ni)                                          \
            acc[mi][ni] = __builtin_amdgcn_mfma_f32_16x16x32_f16(               \
                av[mi], bv[ni], acc[mi][ni], 0, 0, 0);                          \
    __builtin_amdgcn_s_setprio(0);                                              \
    if (PF){                                                                    \
        const int nb = (((T) + 3) & 3) * 16384;                                 \
        GLOAD_LDS(gB0 + (size_t)((T) + 3) * 32, lds + nb + dB0);                \
        GLOAD_LDS(gB1 + (size_t)((T) + 3) * 32, lds + nb + dB1);                \
    }                                                                           \
    f16x8 aw[4];                                                                \
    _Pragma("unroll")                                                           \
    for (int i = 0; i < 4; ++i)                                                 \
        aw[i] = *reinterpret_cast<const f16x8*>(lds + bb + ard + (4 + i) * 512);\
    __builtin_amdgcn_s_setprio(1);                                              \
    _Pragma("unroll")                                                           \
    for (int mi = 0; mi < 4; ++mi)                                              \
        _Pragma("unroll")                                                       \
        for (int ni = 0; ni < 4; ++ni)                                          \
            acc[4 + mi][ni] = __builtin_amdgcn_mfma_f32_16x16x32_f16(           \
                aw[mi], bv[ni], acc[4 + mi][ni], 0, 0, 0);                      \
    __builtin_amdgcn_s_setprio(0);                                              \
  }

__global__ __launch_bounds__(512, 2) void versor_gemm_sc(
    const short* __restrict__ Qbase, const short* __restrict__ Kbase,
    int K, float* __restrict__ OutP,
    const float* __restrict__ NqP, const float* __restrict__ NkP,
    const float* __restrict__ LamP)
{
    extern __shared__ short lds[];   // 4 bufs x (A 8192 | B 8192) shorts

    const int tid  = threadIdx.x;
    const int lane = tid & 63;
    const int wid  = tid >> 6;
    const int wm   = wid >> 2;
    const int wn   = wid & 3;
    const int z    = blockIdx.z;

    const int b = z >> 3, h = z & 7;
    const size_t off = (size_t)b * 1024 * 4096 + (size_t)h * 512;
    const short* A = Qbase + off;
    const short* B = Kbase + off;
    const int lda = 4096, ldb = 4096;
    const int row0 = blockIdx.y * 256;
    const int col0 = blockIdx.x * 256;

    const int jsw = ((lane & 3) ^ ((lane >> 3) & 3)) * 8;
    const short* gA0 = A + (size_t)(row0 + wid * 32 + (lane >> 2)) * lda + jsw;
    const short* gA1 = gA0 + (size_t)16 * lda;
    const short* gB0 = B + (size_t)(col0 + wid * 32 + (lane >> 2)) * ldb + jsw;
    const short* gB1 = gB0 + (size_t)16 * ldb;
    const int dA0 = wid * 1024, dA1 = dA0 + 512;
    const int dB0 = 8192 + wid * 1024, dB1 = dB0 + 512;

    const int swz = ((lane >> 4) ^ (((lane & 15) >> 1) & 3)) * 8;
    const int ard = (wm * 128 + (lane & 15)) * 32 + swz;
    const int brd = 8192 + (wn * 64 + (lane & 15)) * 32 + swz;

    f32x4 acc[8][4];
    #pragma unroll
    for (int i = 0; i < 8; ++i)
        #pragma unroll
        for (int j = 0; j < 4; ++j)
            acc[i][j] = (f32x4){0.f, 0.f, 0.f, 0.f};

    const int NT = K >> 5;   // 16

    #pragma unroll
    for (int pt = 0; pt < 3; ++pt){
        const int bb = pt * 16384;
        GLOAD_LDS(gA0 + pt * 32, lds + bb + dA0);
        GLOAD_LDS(gA1 + pt * 32, lds + bb + dA1);
        GLOAD_LDS(gB0 + pt * 32, lds + bb + dB0);
        GLOAD_LDS(gB1 + pt * 32, lds + bb + dB1);
    }

    for (int t = 0; t < NT - 2; ++t)
        SC_TILE(t, 8, (t + 3 < NT))
    SC_TILE(NT - 2, 4, false)
    SC_TILE(NT - 1, 0, false)

    const int rb = row0 + wm * 128 + (lane >> 4) * 4;
    const int cb = col0 + wn * 64 + (lane & 15);

    float* Of = OutP + (size_t)z * 1024 * 1024;
    const float lam = *LamP;
    const float* nq = NqP + z * 1024;
    const float* nk = NkP + z * 1024;
    #pragma unroll
    for (int mi = 0; mi < 8; ++mi)
        #pragma unroll
        for (int j = 0; j < 4; ++j){
            const int r = rb + mi * 16 + j;
            const float qn = nq[r];
            #pragma unroll
            for (int ni = 0; ni < 4; ++ni){
                const int c = cb + ni * 16;
                const float sc = acc[mi][ni][j];
                const float tq = sqrtf(fmaxf(qn * nk[c] - sc * sc, 0.0f) + 1e-6f);
                Of[(size_t)r * 1024 + c] = 0.25f * (sc + lam * tq);
            }
        }
}

// =======================================================================
extern "C" void kernel_launch(void* const* d_in, const int* in_sizes, int n_in,
                              void* d_out, int out_size, void* d_ws, size_t ws_size,
                              hipStream_t stream)
{
    (void)in_sizes; (void)n_in; (void)out_size; (void)ws_size;
    const float* x   = (const float*)d_in[0];
    const float* Wq  = (const float*)d_in[1];
    const float* Wk  = (const float*)d_in[2];
    const float* Wv  = (const float*)d_in[3];
    const float* Wo  = (const float*)d_in[4];
    const float* lam = (const float*)d_in[5];
    float* out = (float*)d_out;
    char*  ws  = (char*)d_ws;

    // workspace layout (~160.2 MB peak)
    short* Xf   = (short*)(ws);                             // 16 MB; later attn-out
    short* WmT3 = (short*)(ws + (16u  << 20));              // 96 MB (q,k,v); dead after QKV
    short* Qf   = (short*)(ws + (112u << 20));              // 16 MB
    short* Kf   = (short*)(ws + (128u << 20));              // 16 MB
    short* Vt   = (short*)(ws + (144u << 20));              // 16 MB (B,H,512,1024) f16
    float* Nq   = (float*)(ws + (160u << 20));              // 64 KB
    float* Nk   = (float*)(ws + (160u << 20) + (64u << 10));// 64 KB
    float* Sc   = (float*)(ws + (16u  << 20));              // 64 MB, overlays WmT3[0:64MB]
    short* WmTo = (short*)(ws + (80u  << 20));              // 32 MB, overlays WmT3[64:96MB]
    short* Attn = Xf;                                       // 16 MB, overlays Xf

    const int DYN_LDS = 131072;
    hipFuncSetAttribute(reinterpret_cast<const void*>(versor_gemm_sc),
                        hipFuncAttributeMaxDynamicSharedMemorySize, DYN_LDS);

    dim3 blk(256), blk8(512);
    cast_f32_f16<<<4096, blk, 0, stream>>>(x, Xf);

    dim3 gw3(8192, 3);
    build_wmat3<<<gw3, blk, 0, stream>>>(Wq, Wk, Wv, WmT3);

    // fused QKV: A=Xf (2048x4096), B=WmT3 stack (12288x4096); 1536 blocks
    // = exactly 2 rounds at 3 blocks/CU.
    dim3 gqkv(96, 16, 1);
    versor_gemm_r3<0><<<gqkv, blk, 0, stream>>>(
        Xf, 4096, WmT3, 4096, 4096, nullptr, Qf, Kf, Vt);

    row_norms<<<4096, blk, 0, stream>>>(Qf, Kf, Nq, Nk);

    build_wmat<<<8192, blk, 0, stream>>>(Wo, WmTo);

    dim3 gsc(4, 4, 16);      // 256 blocks, 1/CU
    versor_gemm_sc<<<gsc, blk8, DYN_LDS, stream>>>(Qf, Kf, 512, Sc, Nq, Nk, lam);
    softmax_rows<<<4096, blk, 0, stream>>>(Sc);

    dim3 gpv(4, 8, 16);      // 512 blocks
    versor_gemm_r3<5><<<gpv, blk, 0, stream>>>(
        (const short*)Sc, 2048, Vt, 1024, 1024, Attn, nullptr, nullptr, nullptr);

    dim3 gfin(32, 16, 1);    // 512 blocks
    versor_gemm_r3<3><<<gfin, blk, 0, stream>>>(
        Attn, 4096, WmTo, 4096, 4096, out, nullptr, nullptr, nullptr);
}

// Round 7
// 551.380 us; speedup vs baseline: 1.5874x; 1.0042x over previous
//
#include <hip/hip_runtime.h>
#include <stdint.h>

typedef __attribute__((ext_vector_type(4))) float    f32x4;
typedef __attribute__((ext_vector_type(8))) short    s16x8;
typedef __attribute__((ext_vector_type(4))) short    s16x4;
typedef __attribute__((ext_vector_type(8))) _Float16 f16x8;

#define DEV __device__ __forceinline__

// sign of e_a * e_b in Cl(4,1), METRIC=(1,1,1,1,-1): C[a,b,a^b]
DEV float blade_sign(int a, int b){
    int s = 0, t = a >> 1;
    while (t){ s += __popc(t & b); t >>= 1; }
    float sg = (s & 1) ? -1.0f : 1.0f;
    return ((a & b) & 16) ? -sg : sg;
}
DEV short f2h(float v){
    _Float16 h = (_Float16)v;                 // RNE f32->f16
    return __builtin_bit_cast(short, h);
}
DEV float h2f(short b){
    return (float)__builtin_bit_cast(_Float16, b);
}
DEV void wait_vm(int n){                      // literal-arg folded vmcnt
    if (n == 8)      asm volatile("s_waitcnt vmcnt(8)" ::: "memory");
    else if (n == 4) asm volatile("s_waitcnt vmcnt(4)" ::: "memory");
    else             asm volatile("s_waitcnt vmcnt(0)" ::: "memory");
}

// ---------------- cast x (f32) -> f16, 8 elems/thread ----------------
__global__ __launch_bounds__(256) void cast_f32_f16(const float* __restrict__ in,
                                                    short* __restrict__ out){
    const size_t idx = (size_t)blockIdx.x * 256 + threadIdx.x;
    const float4* p = reinterpret_cast<const float4*>(in) + idx * 2;
    float4 a = p[0], b = p[1];
    s16x8 o;
    o[0]=f2h(a.x); o[1]=f2h(a.y); o[2]=f2h(a.z); o[3]=f2h(a.w);
    o[4]=f2h(b.x); o[5]=f2h(b.y); o[6]=f2h(b.z); o[7]=f2h(b.w);
    *reinterpret_cast<s16x8*>(out + idx * 8) = o;
}

// ------- build WmatT f16: WmT[o*32+kb][i*32+l] = W[o,i,kb^l]*C[kb^l,l,kb] -------
DEV void build_wmat_body(const float* __restrict__ W, short* __restrict__ WmT,
                         int idx){
    const int n  = idx >> 9;
    const int kg = idx & 511;
    const int o = n >> 5, kb = n & 31;
    const int i = kg >> 2, l0 = (kg & 3) * 8;
    const float* wrow = W + (size_t)(o * 128 + i) * 32;
    s16x8 v;
    #pragma unroll
    for (int e = 0; e < 8; ++e){
        const int l = l0 + e, j = kb ^ l;
        v[e] = f2h(wrow[j] * blade_sign(j, l));
    }
    *reinterpret_cast<s16x8*>(WmT + (size_t)n * 4096 + kg * 8) = v;
}

__global__ __launch_bounds__(256) void build_wmat(const float* __restrict__ W,
                                                  short* __restrict__ WmT){
    build_wmat_body(W, WmT, blockIdx.x * 256 + threadIdx.x);
}

__global__ __launch_bounds__(256) void build_wmat3(const float* __restrict__ Wq,
                                                   const float* __restrict__ Wk,
                                                   const float* __restrict__ Wv,
                                                   short* __restrict__ WmT3){
    const int w = blockIdx.y;
    const float* W = (w == 0) ? Wq : ((w == 1) ? Wk : Wv);
    build_wmat_body(W, WmT3 + (size_t)w * 4096 * 4096,
                    blockIdx.x * 256 + threadIdx.x);
}

// ---------------- per-(b,h,s) norms over 512 features (q and k) ----------------
__global__ __launch_bounds__(256) void row_norms(const short* __restrict__ Q,
                                                 const short* __restrict__ Kq,
                                                 float* __restrict__ Nq,
                                                 float* __restrict__ Nk){
    const int row  = blockIdx.x * 4 + (threadIdx.x >> 6);
    const int lane = threadIdx.x & 63;
    const int b = row >> 13, h = (row >> 10) & 7, s = row & 1023;
    const size_t off = ((size_t)(b * 1024 + s)) * 4096 + h * 512 + lane * 8;
    s16x8 a = *reinterpret_cast<const s16x8*>(Q + off);
    s16x8 c = *reinterpret_cast<const s16x8*>(Kq + off);
    float sq = 0.f, sk = 0.f;
    #pragma unroll
    for (int e = 0; e < 8; ++e){
        float fa = h2f(a[e]); sq = fmaf(fa, fa, sq);
        float fc = h2f(c[e]); sk = fmaf(fc, fc, sk);
    }
    #pragma unroll
    for (int m = 1; m < 64; m <<= 1){
        sq += __shfl_xor(sq, m);
        sk += __shfl_xor(sk, m);
    }
    if (lane == 0){ Nq[row] = sq; Nk[row] = sk; }
}

// -------- softmax per row, in place: read 1024 f32, write 1024 f16 at row head --------
__global__ __launch_bounds__(256) void softmax_rows(float* __restrict__ Sc){
    const int row  = blockIdx.x * 4 + (threadIdx.x >> 6);
    const int lane = threadIdx.x & 63;
    float* p = Sc + (size_t)row * 1024;
    float v[16];
    float mx = -3.0e38f;
    #pragma unroll
    for (int j = 0; j < 16; ++j){ v[j] = p[lane + j * 64]; mx = fmaxf(mx, v[j]); }
    #pragma unroll
    for (int m = 1; m < 64; m <<= 1) mx = fmaxf(mx, __shfl_xor(mx, m));
    float sum = 0.f;
    #pragma unroll
    for (int j = 0; j < 16; ++j){ v[j] = __expf(v[j] - mx); sum += v[j]; }
    #pragma unroll
    for (int m = 1; m < 64; m <<= 1) sum += __shfl_xor(sum, m);
    const float inv = 1.0f / sum;
    short* pb = reinterpret_cast<short*>(p);
    #pragma unroll
    for (int j = 0; j < 16; ++j) pb[lane + j * 64] = f2h(v[j] * inv);
}

#define GLOAD_LDS(gp, lp) \
    __builtin_amdgcn_global_load_lds( \
        (const __attribute__((address_space(1))) void*)(const void*)(gp), \
        (__attribute__((address_space(3))) void*)(void*)(lp), 16, 0, 0)

// =======================================================================
// 128x128 ring-3 pipelined GEMM: BK=32, 4 waves, 48 KB LDS -> 3 blocks/CU.
// Counted vmcnt(4) (2-tile prefetch margin), peeled last tile vmcnt(0).
// XOR swizzle on 16B chunks (0 bank conflicts, verified R5/R6). setprio.
// CPX>0: XCD-ownership block swizzle — xcd = wg&7 owns CPX col-panels;
// row-fast within XCD so each B panel is fetched by ONE XCD and stays
// L2-resident across the 16 row-blocks (requires gridDim.y==16, 8 XCDs).
// EPI: 0 = fused QKV (col0>>12 selects Q*SIG / K / V^T)
//      3 = final (norm, f32)    5 = PV (f16, batched over z)
// =======================================================================
#define R3_TILE(T, WN, PF)                                                      \
  {                                                                             \
    const int bb = cur * 8192;                                                  \
    wait_vm(WN);                                                                \
    __builtin_amdgcn_s_barrier();                                               \
    asm volatile("" ::: "memory");                                              \
    __builtin_amdgcn_sched_barrier(0);                                          \
    const int sb = stg * 8192;                                                  \
    if (PF){                                                                    \
        GLOAD_LDS(gA0 + (size_t)((T) + 2) * 32, lds + sb + dA0);                \
        GLOAD_LDS(gA1 + (size_t)((T) + 2) * 32, lds + sb + dA1);                \
    }                                                                           \
    f16x8 av[4], bv[4];                                                         \
    _Pragma("unroll")                                                           \
    for (int i = 0; i < 4; ++i)                                                 \
        av[i] = *reinterpret_cast<const f16x8*>(lds + bb + ard + i * 512);      \
    bv[0] = *reinterpret_cast<const f16x8*>(lds + bb + brd + 0 * 512);          \
    bv[1] = *reinterpret_cast<const f16x8*>(lds + bb + brd + 1 * 512);          \
    __builtin_amdgcn_s_setprio(1);                                              \
    _Pragma("unroll")                                                           \
    for (int mi = 0; mi < 4; ++mi)                                              \
        _Pragma("unroll")                                                       \
        for (int ni = 0; ni < 2; ++ni)                                          \
            acc[mi][ni] = __builtin_amdgcn_mfma_f32_16x16x32_f16(               \
                av[mi], bv[ni], acc[mi][ni], 0, 0, 0);                          \
    __builtin_amdgcn_s_setprio(0);                                              \
    if (PF){                                                                    \
        GLOAD_LDS(gB0 + (size_t)((T) + 2) * 32, lds + sb + dB0);                \
        GLOAD_LDS(gB1 + (size_t)((T) + 2) * 32, lds + sb + dB1);                \
    }                                                                           \
    bv[2] = *reinterpret_cast<const f16x8*>(lds + bb + brd + 2 * 512);          \
    bv[3] = *reinterpret_cast<const f16x8*>(lds + bb + brd + 3 * 512);          \
    __builtin_amdgcn_s_setprio(1);                                              \
    _Pragma("unroll")                                                           \
    for (int mi = 0; mi < 4; ++mi)                                              \
        _Pragma("unroll")                                                       \
        for (int ni = 2; ni < 4; ++ni)                                          \
            acc[mi][ni] = __builtin_amdgcn_mfma_f32_16x16x32_f16(               \
                av[mi], bv[ni], acc[mi][ni], 0, 0, 0);                          \
    __builtin_amdgcn_s_setprio(0);                                              \
    cur = (cur == 2) ? 0 : cur + 1;                                             \
    stg = (stg == 2) ? 0 : stg + 1;                                             \
  }

template<int EPI, int CPX>
__global__ __launch_bounds__(256, 3) void versor_gemm_r3(
    const short* __restrict__ Abase, int lda,
    const short* __restrict__ Bbase, int ldb,
    int K, void* __restrict__ OutP,
    short* __restrict__ OQ, short* __restrict__ OK, short* __restrict__ OV)
{
    __shared__ short lds[3 * 8192];   // 3 bufs x (A 128x32 | B 128x32)

    const int tid  = threadIdx.x;
    const int lane = tid & 63;
    const int wid  = tid >> 6;        // 0..3
    const int wr   = wid >> 1;
    const int wc   = wid & 1;
    const int z    = blockIdx.z;

    // ---- block swizzle: XCD col-panel ownership (bijective) ----
    int bn, bm;
    if constexpr (CPX > 0){
        const int wg  = blockIdx.x + blockIdx.y * gridDim.x;
        const int xcd = wg & 7;
        const int u   = wg >> 3;
        bm = u & 15;                  // row-fast: B panel L2-resident per XCD
        bn = xcd * CPX + (u >> 4);
    } else {
        bn = blockIdx.x; bm = blockIdx.y;
    }

    const short* A = Abase;
    const short* B = Bbase;
    if constexpr (EPI == 5){          // PV: probs + V^T slices
        A += (size_t)z * 1024 * 2048;
        B += (size_t)z * 512 * 1024;
    }
    const int row0 = bm * 128;
    const int col0 = bn * 128;

    // staging: chunk (r*256 + wid*64 + lane) -> LDS shorts (r*2048 + wid*512 + lane*8)
    const int jsw = ((lane & 3) ^ ((lane >> 3) & 3)) * 8;
    const short* gA0 = A + (size_t)(row0 + wid * 16 + (lane >> 2)) * lda + jsw;
    const short* gA1 = gA0 + (size_t)64 * lda;
    const short* gB0 = B + (size_t)(col0 + wid * 16 + (lane >> 2)) * ldb + jsw;
    const short* gB1 = gB0 + (size_t)64 * ldb;
    const int dA0 = wid * 512,        dA1 = 2048 + wid * 512;
    const int dB0 = 4096 + wid * 512, dB1 = 6144 + wid * 512;

    // ds_read frag bases (swizzled, lane-only XOR)
    const int swz = ((lane >> 4) ^ (((lane & 15) >> 1) & 3)) * 8;
    const int ard = (wr * 64 + (lane & 15)) * 32 + swz;          // + mi*512
    const int brd = 4096 + (wc * 64 + (lane & 15)) * 32 + swz;   // + ni*512

    f32x4 acc[4][4];
    #pragma unroll
    for (int i = 0; i < 4; ++i)
        #pragma unroll
        for (int j = 0; j < 4; ++j)
            acc[i][j] = (f32x4){0.f, 0.f, 0.f, 0.f};

    const int NT = K >> 5;

    // prologue: stage tiles 0,1 into slots 0,1
    #pragma unroll
    for (int pt = 0; pt < 2; ++pt){
        const int sb = pt * 8192;
        GLOAD_LDS(gA0 + pt * 32, lds + sb + dA0);
        GLOAD_LDS(gA1 + pt * 32, lds + sb + dA1);
        GLOAD_LDS(gB0 + pt * 32, lds + sb + dB0);
        GLOAD_LDS(gB1 + pt * 32, lds + sb + dB1);
    }

    int cur = 0, stg = 2;
    for (int t = 0; t < NT - 1; ++t)
        R3_TILE(t, 4, (t + 2 < NT))
    R3_TILE(NT - 1, 0, false)

    // ---------------- epilogue ----------------
    const int rb = row0 + wr * 64 + (lane >> 4) * 4;   // + mi*16 + j
    const int cb = col0 + wc * 64 + (lane & 15);       // + ni*16

    if constexpr (EPI == 0 || EPI == 3){
        // normalize each 32-col blade group to unit RMS
        #pragma unroll
        for (int mi = 0; mi < 4; ++mi){
            #pragma unroll
            for (int g = 0; g < 2; ++g){
                f32x4 a0 = acc[mi][2 * g], a1 = acc[mi][2 * g + 1];
                f32x4 ss = a0 * a0 + a1 * a1;
                #pragma unroll
                for (int m = 1; m < 16; m <<= 1){
                    ss.x += __shfl_xor(ss.x, m);
                    ss.y += __shfl_xor(ss.y, m);
                    ss.z += __shfl_xor(ss.z, m);
                    ss.w += __shfl_xor(ss.w, m);
                }
                f32x4 inv;
                inv.x = 1.0f / sqrtf(ss.x * 0.03125f + 1e-6f);
                inv.y = 1.0f / sqrtf(ss.y * 0.03125f + 1e-6f);
                inv.z = 1.0f / sqrtf(ss.z * 0.03125f + 1e-6f);
                inv.w = 1.0f / sqrtf(ss.w * 0.03125f + 1e-6f);
                acc[mi][2 * g]     = a0 * inv;
                acc[mi][2 * g + 1] = a1 * inv;
            }
        }
    }

    if constexpr (EPI == 0){
        const int zsel = col0 >> 12;          // 0:Q 1:K 2:V
        const int cbm  = (col0 & 4095) + wc * 64 + (lane & 15);
        if (zsel == 0){
            const float sg0 = blade_sign(lane & 15, lane & 15);
            const float sg1 = blade_sign(16 | (lane & 15), 16 | (lane & 15));
            #pragma unroll
            for (int mi = 0; mi < 4; ++mi)
                #pragma unroll
                for (int ni = 0; ni < 4; ++ni){
                    const f32x4 v = acc[mi][ni] * ((ni & 1) ? sg1 : sg0);
                    #pragma unroll
                    for (int j = 0; j < 4; ++j)
                        OQ[(size_t)(rb + mi * 16 + j) * 4096 + (cbm + ni * 16)] = f2h(v[j]);
                }
        } else if (zsel == 1){
            #pragma unroll
            for (int mi = 0; mi < 4; ++mi)
                #pragma unroll
                for (int ni = 0; ni < 4; ++ni)
                    #pragma unroll
                    for (int j = 0; j < 4; ++j)
                        OK[(size_t)(rb + mi * 16 + j) * 4096 + (cbm + ni * 16)] = f2h(acc[mi][ni][j]);
        } else {
            // V^T store: (b,h,f,t), 4 consecutive t per lane
            #pragma unroll
            for (int mi = 0; mi < 4; ++mi){
                const int r = rb + mi * 16;
                const int b = r >> 10, tt = r & 1023;
                #pragma unroll
                for (int ni = 0; ni < 4; ++ni){
                    const int c = cbm + ni * 16;
                    const int h = c >> 9, f = c & 511;
                    s16x4 pv;
                    #pragma unroll
                    for (int j = 0; j < 4; ++j) pv[j] = f2h(acc[mi][ni][j]);
                    *reinterpret_cast<s16x4*>(OV + ((size_t)((b * 8 + h) * 512 + f)) * 1024 + tt) = pv;
                }
            }
        }
    }
    if constexpr (EPI == 3){
        float* Of = (float*)OutP;
        #pragma unroll
        for (int mi = 0; mi < 4; ++mi)
            #pragma unroll
            for (int ni = 0; ni < 4; ++ni)
                #pragma unroll
                for (int j = 0; j < 4; ++j)
                    Of[(size_t)(rb + mi * 16 + j) * 4096 + (cb + ni * 16)] = acc[mi][ni][j];
    }
    if constexpr (EPI == 5){   // PV out -> attnout[(b*1024+s)*4096 + h*512 + f] f16
        short* Ob = (short*)OutP;
        const int b = z >> 3, h = z & 7;
        #pragma unroll
        for (int mi = 0; mi < 4; ++mi)
            #pragma unroll
            for (int ni = 0; ni < 4; ++ni)
                #pragma unroll
                for (int j = 0; j < 4; ++j)
                    Ob[(size_t)(b * 1024 + rb + mi * 16 + j) * 4096 + h * 512 + (cb + ni * 16)]
                        = f2h(acc[mi][ni][j]);
    }
}

// =======================================================================
// Scores kernel (256x256, 8 waves, ring-4, dyn 128KB LDS) with torque
// epilogue. Peeled tail (vmcnt 8 -> 4 -> 0).
// =======================================================================
#define SC_TILE(T, WN, PF)                                                      \
  {                                                                             \
    const int bb = ((T) & 3) * 16384;                                           \
    wait_vm(WN);                                                                \
    __builtin_amdgcn_s_barrier();                                               \
    asm volatile("" ::: "memory");                                              \
    __builtin_amdgcn_sched_barrier(0);                                          \
    if (PF){                                                                    \
        const int nb = (((T) + 3) & 3) * 16384;                                 \
        GLOAD_LDS(gA0 + (size_t)((T) + 3) * 32, lds + nb + dA0);                \
        GLOAD_LDS(gA1 + (size_t)((T) + 3) * 32, lds + nb + dA1);                \
    }                                                                           \
    f16x8 av[4], bv[4];                                                         \
    _Pragma("unroll")                                                           \
    for (int i = 0; i < 4; ++i){                                                \
        av[i] = *reinterpret_cast<const f16x8*>(lds + bb + ard + i * 512);      \
        bv[i] = *reinterpret_cast<const f16x8*>(lds + bb + brd + i * 512);      \
    }                                                                           \
    __builtin_amdgcn_s_setprio(1);                                              \
    _Pragma("unroll")                                                           \
    for (int mi = 0; mi < 4; ++mi)                                              \
        _Pragma("unroll")                                                       \
        for (int ni = 0; ni < 4; ++ni)                                          \
            acc[mi][ni] = __builtin_amdgcn_mfma_f32_16x16x32_f16(               \
                av[mi], bv[ni], acc[mi][ni], 0, 0, 0);                          \
    __builtin_amdgcn_s_setprio(0);                                              \
    if (PF){                                                                    \
        const int nb = (((T) + 3) & 3) * 16384;                                 \
        GLOAD_LDS(gB0 + (size_t)((T) + 3) * 32, lds + nb + dB0);                \
        GLOAD_LDS(gB1 + (size_t)((T) + 3) * 32, lds + nb + dB1);                \
    }                                                                           \
    f16x8 aw[4];                                                                \
    _Pragma("unroll")                                                           \
    for (int i = 0; i < 4; ++i)                                                 \
        aw[i] = *reinterpret_cast<const f16x8*>(lds + bb + ard + (4 + i) * 512);\
    __builtin_amdgcn_s_setprio(1);                                              \
    _Pragma("unroll")                                                           \
    for (int mi = 0; mi < 4; ++mi)                                              \
        _Pragma("unroll")                                                       \
        for (int ni = 0; ni < 4; ++ni)                                          \
            acc[4 + mi][ni] = __builtin_amdgcn_mfma_f32_16x16x32_f16(           \
                aw[mi], bv[ni], acc[4 + mi][ni], 0, 0, 0);                      \
    __builtin_amdgcn_s_setprio(0);                                              \
  }

__global__ __launch_bounds__(512, 2) void versor_gemm_sc(
    const short* __restrict__ Qbase, const short* __restrict__ Kbase,
    int K, float* __restrict__ OutP,
    const float* __restrict__ NqP, const float* __restrict__ NkP,
    const float* __restrict__ LamP)
{
    extern __shared__ short lds[];   // 4 bufs x (A 8192 | B 8192) shorts

    const int tid  = threadIdx.x;
    const int lane = tid & 63;
    const int wid  = tid >> 6;
    const int wm   = wid >> 2;
    const int wn   = wid & 3;
    const int z    = blockIdx.z;

    const int b = z >> 3, h = z & 7;
    const size_t off = (size_t)b * 1024 * 4096 + (size_t)h * 512;
    const short* A = Qbase + off;
    const short* B = Kbase + off;
    const int lda = 4096, ldb = 4096;
    const int row0 = blockIdx.y * 256;
    const int col0 = blockIdx.x * 256;

    const int jsw = ((lane & 3) ^ ((lane >> 3) & 3)) * 8;
    const short* gA0 = A + (size_t)(row0 + wid * 32 + (lane >> 2)) * lda + jsw;
    const short* gA1 = gA0 + (size_t)16 * lda;
    const short* gB0 = B + (size_t)(col0 + wid * 32 + (lane >> 2)) * ldb + jsw;
    const short* gB1 = gB0 + (size_t)16 * ldb;
    const int dA0 = wid * 1024, dA1 = dA0 + 512;
    const int dB0 = 8192 + wid * 1024, dB1 = dB0 + 512;

    const int swz = ((lane >> 4) ^ (((lane & 15) >> 1) & 3)) * 8;
    const int ard = (wm * 128 + (lane & 15)) * 32 + swz;
    const int brd = 8192 + (wn * 64 + (lane & 15)) * 32 + swz;

    f32x4 acc[8][4];
    #pragma unroll
    for (int i = 0; i < 8; ++i)
        #pragma unroll
        for (int j = 0; j < 4; ++j)
            acc[i][j] = (f32x4){0.f, 0.f, 0.f, 0.f};

    const int NT = K >> 5;   // 16

    #pragma unroll
    for (int pt = 0; pt < 3; ++pt){
        const int bb = pt * 16384;
        GLOAD_LDS(gA0 + pt * 32, lds + bb + dA0);
        GLOAD_LDS(gA1 + pt * 32, lds + bb + dA1);
        GLOAD_LDS(gB0 + pt * 32, lds + bb + dB0);
        GLOAD_LDS(gB1 + pt * 32, lds + bb + dB1);
    }

    for (int t = 0; t < NT - 2; ++t)
        SC_TILE(t, 8, (t + 3 < NT))
    SC_TILE(NT - 2, 4, false)
    SC_TILE(NT - 1, 0, false)

    const int rb = row0 + wm * 128 + (lane >> 4) * 4;
    const int cb = col0 + wn * 64 + (lane & 15);

    float* Of = OutP + (size_t)z * 1024 * 1024;
    const float lam = *LamP;
    const float* nq = NqP + z * 1024;
    const float* nk = NkP + z * 1024;
    #pragma unroll
    for (int mi = 0; mi < 8; ++mi)
        #pragma unroll
        for (int j = 0; j < 4; ++j){
            const int r = rb + mi * 16 + j;
            const float qn = nq[r];
            #pragma unroll
            for (int ni = 0; ni < 4; ++ni){
                const int c = cb + ni * 16;
                const float sc = acc[mi][ni][j];
                const float tq = sqrtf(fmaxf(qn * nk[c] - sc * sc, 0.0f) + 1e-6f);
                Of[(size_t)r * 1024 + c] = 0.25f * (sc + lam * tq);
            }
        }
}

// =======================================================================
extern "C" void kernel_launch(void* const* d_in, const int* in_sizes, int n_in,
                              void* d_out, int out_size, void* d_ws, size_t ws_size,
                              hipStream_t stream)
{
    (void)in_sizes; (void)n_in; (void)out_size; (void)ws_size;
    const float* x   = (const float*)d_in[0];
    const float* Wq  = (const float*)d_in[1];
    const float* Wk  = (const float*)d_in[2];
    const float* Wv  = (const float*)d_in[3];
    const float* Wo  = (const float*)d_in[4];
    const float* lam = (const float*)d_in[5];
    float* out = (float*)d_out;
    char*  ws  = (char*)d_ws;

    // workspace layout (~160.2 MB peak)
    short* Xf   = (short*)(ws);                             // 16 MB; later attn-out
    short* WmT3 = (short*)(ws + (16u  << 20));              // 96 MB (q,k,v); dead after QKV
    short* Qf   = (short*)(ws + (112u << 20));              // 16 MB
    short* Kf   = (short*)(ws + (128u << 20));              // 16 MB
    short* Vt   = (short*)(ws + (144u << 20));              // 16 MB (B,H,512,1024) f16
    float* Nq   = (float*)(ws + (160u << 20));              // 64 KB
    float* Nk   = (float*)(ws + (160u << 20) + (64u << 10));// 64 KB
    float* Sc   = (float*)(ws + (16u  << 20));              // 64 MB, overlays WmT3[0:64MB]
    short* WmTo = (short*)(ws + (80u  << 20));              // 32 MB, overlays WmT3[64:96MB]
    short* Attn = Xf;                                       // 16 MB, overlays Xf

    const int DYN_LDS = 131072;
    hipFuncSetAttribute(reinterpret_cast<const void*>(versor_gemm_sc),
                        hipFuncAttributeMaxDynamicSharedMemorySize, DYN_LDS);

    dim3 blk(256), blk8(512);
    cast_f32_f16<<<4096, blk, 0, stream>>>(x, Xf);

    dim3 gw3(8192, 3);
    build_wmat3<<<gw3, blk, 0, stream>>>(Wq, Wk, Wv, WmT3);

    // fused QKV: A=Xf (2048x4096), B=WmT3 stack (12288x4096); 1536 blocks,
    // XCD swizzle: each XCD owns 12 col-panels (CPX=12), row-fast within.
    dim3 gqkv(96, 16, 1);
    versor_gemm_r3<0, 12><<<gqkv, blk, 0, stream>>>(
        Xf, 4096, WmT3, 4096, 4096, nullptr, Qf, Kf, Vt);

    row_norms<<<4096, blk, 0, stream>>>(Qf, Kf, Nq, Nk);

    build_wmat<<<8192, blk, 0, stream>>>(Wo, WmTo);

    dim3 gsc(4, 4, 16);      // 256 blocks, 1/CU
    versor_gemm_sc<<<gsc, blk8, DYN_LDS, stream>>>(Qf, Kf, 512, Sc, Nq, Nk, lam);
    softmax_rows<<<4096, blk, 0, stream>>>(Sc);

    dim3 gpv(4, 8, 16);      // 512 blocks
    versor_gemm_r3<5, 0><<<gpv, blk, 0, stream>>>(
        (const short*)Sc, 2048, Vt, 1024, 1024, Attn, nullptr, nullptr, nullptr);

    dim3 gfin(32, 16, 1);    // 512 blocks, XCD swizzle CPX=4
    versor_gemm_r3<3, 4><<<gfin, blk, 0, stream>>>(
        Attn, 4096, WmTo, 4096, 4096, out, nullptr, nullptr, nullptr);
}

// Round 8
// 525.717 us; speedup vs baseline: 1.6648x; 1.0488x over previous
//
#include <hip/hip_runtime.h>
#include <stdint.h>

typedef __attribute__((ext_vector_type(4))) float    f32x4;
typedef __attribute__((ext_vector_type(8))) short    s16x8;
typedef __attribute__((ext_vector_type(4))) short    s16x4;
typedef __attribute__((ext_vector_type(8))) _Float16 f16x8;

#define DEV __device__ __forceinline__

// sign of e_a * e_b in Cl(4,1), METRIC=(1,1,1,1,-1): C[a,b,a^b]
DEV float blade_sign(int a, int b){
    int s = 0, t = a >> 1;
    while (t){ s += __popc(t & b); t >>= 1; }
    float sg = (s & 1) ? -1.0f : 1.0f;
    return ((a & b) & 16) ? -sg : sg;
}
DEV short f2h(float v){
    _Float16 h = (_Float16)v;                 // RNE f32->f16
    return __builtin_bit_cast(short, h);
}
DEV float h2f(short b){
    return (float)__builtin_bit_cast(_Float16, b);
}
DEV void wait_vm(int n){                      // literal-arg folded vmcnt
    if (n == 12)     asm volatile("s_waitcnt vmcnt(12)" ::: "memory");
    else if (n == 8) asm volatile("s_waitcnt vmcnt(8)" ::: "memory");
    else if (n == 6) asm volatile("s_waitcnt vmcnt(6)" ::: "memory");
    else if (n == 4) asm volatile("s_waitcnt vmcnt(4)" ::: "memory");
    else             asm volatile("s_waitcnt vmcnt(0)" ::: "memory");
}

// ---------------- cast x (f32) -> f16, 8 elems/thread ----------------
__global__ __launch_bounds__(256) void cast_f32_f16(const float* __restrict__ in,
                                                    short* __restrict__ out){
    const size_t idx = (size_t)blockIdx.x * 256 + threadIdx.x;
    const float4* p = reinterpret_cast<const float4*>(in) + idx * 2;
    float4 a = p[0], b = p[1];
    s16x8 o;
    o[0]=f2h(a.x); o[1]=f2h(a.y); o[2]=f2h(a.z); o[3]=f2h(a.w);
    o[4]=f2h(b.x); o[5]=f2h(b.y); o[6]=f2h(b.z); o[7]=f2h(b.w);
    *reinterpret_cast<s16x8*>(out + idx * 8) = o;
}

// ------- build WmatT f16: WmT[o*32+kb][i*32+l] = W[o,i,kb^l]*C[kb^l,l,kb] -------
DEV void build_wmat_body(const float* __restrict__ W, short* __restrict__ WmT,
                         int idx){
    const int n  = idx >> 9;
    const int kg = idx & 511;
    const int o = n >> 5, kb = n & 31;
    const int i = kg >> 2, l0 = (kg & 3) * 8;
    const float* wrow = W + (size_t)(o * 128 + i) * 32;
    s16x8 v;
    #pragma unroll
    for (int e = 0; e < 8; ++e){
        const int l = l0 + e, j = kb ^ l;
        v[e] = f2h(wrow[j] * blade_sign(j, l));
    }
    *reinterpret_cast<s16x8*>(WmT + (size_t)n * 4096 + kg * 8) = v;
}

__global__ __launch_bounds__(256) void build_wmat(const float* __restrict__ W,
                                                  short* __restrict__ WmT){
    build_wmat_body(W, WmT, blockIdx.x * 256 + threadIdx.x);
}

__global__ __launch_bounds__(256) void build_wmat3(const float* __restrict__ Wq,
                                                   const float* __restrict__ Wk,
                                                   const float* __restrict__ Wv,
                                                   short* __restrict__ WmT3){
    const int w = blockIdx.y;
    const float* W = (w == 0) ? Wq : ((w == 1) ? Wk : Wv);
    build_wmat_body(W, WmT3 + (size_t)w * 4096 * 4096,
                    blockIdx.x * 256 + threadIdx.x);
}

// ---------------- per-(b,h,s) norms over 512 features (q and k) ----------------
__global__ __launch_bounds__(256) void row_norms(const short* __restrict__ Q,
                                                 const short* __restrict__ Kq,
                                                 float* __restrict__ Nq,
                                                 float* __restrict__ Nk){
    const int row  = blockIdx.x * 4 + (threadIdx.x >> 6);
    const int lane = threadIdx.x & 63;
    const int b = row >> 13, h = (row >> 10) & 7, s = row & 1023;
    const size_t off = ((size_t)(b * 1024 + s)) * 4096 + h * 512 + lane * 8;
    s16x8 a = *reinterpret_cast<const s16x8*>(Q + off);
    s16x8 c = *reinterpret_cast<const s16x8*>(Kq + off);
    float sq = 0.f, sk = 0.f;
    #pragma unroll
    for (int e = 0; e < 8; ++e){
        float fa = h2f(a[e]); sq = fmaf(fa, fa, sq);
        float fc = h2f(c[e]); sk = fmaf(fc, fc, sk);
    }
    #pragma unroll
    for (int m = 1; m < 64; m <<= 1){
        sq += __shfl_xor(sq, m);
        sk += __shfl_xor(sk, m);
    }
    if (lane == 0){ Nq[row] = sq; Nk[row] = sk; }
}

// -------- softmax per row, in place: read 1024 f32, write 1024 f16 at row head --------
__global__ __launch_bounds__(256) void softmax_rows(float* __restrict__ Sc){
    const int row  = blockIdx.x * 4 + (threadIdx.x >> 6);
    const int lane = threadIdx.x & 63;
    float* p = Sc + (size_t)row * 1024;
    float v[16];
    float mx = -3.0e38f;
    #pragma unroll
    for (int j = 0; j < 16; ++j){ v[j] = p[lane + j * 64]; mx = fmaxf(mx, v[j]); }
    #pragma unroll
    for (int m = 1; m < 64; m <<= 1) mx = fmaxf(mx, __shfl_xor(mx, m));
    float sum = 0.f;
    #pragma unroll
    for (int j = 0; j < 16; ++j){ v[j] = __expf(v[j] - mx); sum += v[j]; }
    #pragma unroll
    for (int m = 1; m < 64; m <<= 1) sum += __shfl_xor(sum, m);
    const float inv = 1.0f / sum;
    short* pb = reinterpret_cast<short*>(p);
    #pragma unroll
    for (int j = 0; j < 16; ++j) pb[lane + j * 64] = f2h(v[j] * inv);
}

#define GLOAD_LDS(gp, lp) \
    __builtin_amdgcn_global_load_lds( \
        (const __attribute__((address_space(1))) void*)(const void*)(gp), \
        (__attribute__((address_space(3))) void*)(void*)(lp), 16, 0, 0)

// =======================================================================
// QKV GEMM, wave-efficient geometry: 256(M)x128(N) tile, BK=32, 4 waves
// (2x2), per-wave output 128x64 (better area/perimeter: 12 ds_read_b128
// per 32 MFMA vs 8 per 16). Ring-3 LDS (3 x 24KB = 72KB dyn) -> 2 blk/CU.
// Counted vmcnt(6) (stage t+2 during t), peeled last tile vmcnt(0).
// XOR chunk swizzle (0 bank conflicts, HW-verified R5-R7). setprio.
// XCD swizzle: xcd owns 12 col-panels, row-fast (grid 96x8, CPX=12).
// B = WmT3 stack (12288 x 4096); col0>>12 selects Q*SIG / K / V^T epi.
// =======================================================================
#define QKV_TILE(T, WN, PF)                                                     \
  {                                                                             \
    const int bb = cur * 12288;                                                 \
    wait_vm(WN);                                                                \
    __builtin_amdgcn_s_barrier();                                               \
    asm volatile("" ::: "memory");                                              \
    __builtin_amdgcn_sched_barrier(0);                                          \
    const int sb = stg * 12288;                                                 \
    if (PF){                                                                    \
        GLOAD_LDS(gA0 + (size_t)((T) + 2) * 32, lds + sb + dA + 0 * 512);       \
        GLOAD_LDS(gA1 + (size_t)((T) + 2) * 32, lds + sb + dA + 1 * 512);       \
        GLOAD_LDS(gA2 + (size_t)((T) + 2) * 32, lds + sb + dA + 2 * 512);       \
        GLOAD_LDS(gA3 + (size_t)((T) + 2) * 32, lds + sb + dA + 3 * 512);       \
    }                                                                           \
    f16x8 av[4], bv[4];                                                         \
    _Pragma("unroll")                                                           \
    for (int i = 0; i < 4; ++i){                                                \
        av[i] = *reinterpret_cast<const f16x8*>(lds + bb + ard + i * 512);      \
        bv[i] = *reinterpret_cast<const f16x8*>(lds + bb + brd + i * 512);      \
    }                                                                           \
    __builtin_amdgcn_s_setprio(1);                                              \
    _Pragma("unroll")                                                           \
    for (int mi = 0; mi < 4; ++mi)                                              \
        _Pragma("unroll")                                                       \
        for (int ni = 0; ni < 4; ++ni)                                          \
            acc[mi][ni] = __builtin_amdgcn_mfma_f32_16x16x32_f16(               \
                av[mi], bv[ni], acc[mi][ni], 0, 0, 0);                          \
    __builtin_amdgcn_s_setprio(0);                                              \
    if (PF){                                                                    \
        GLOAD_LDS(gB0 + (size_t)((T) + 2) * 32, lds + sb + dB + 0 * 512);       \
        GLOAD_LDS(gB1 + (size_t)((T) + 2) * 32, lds + sb + dB + 1 * 512);       \
    }                                                                           \
    f16x8 aw[4];                                                                \
    _Pragma("unroll")                                                           \
    for (int i = 0; i < 4; ++i)                                                 \
        aw[i] = *reinterpret_cast<const f16x8*>(lds + bb + ard + (4 + i) * 512);\
    __builtin_amdgcn_s_setprio(1);                                              \
    _Pragma("unroll")                                                           \
    for (int mi = 0; mi < 4; ++mi)                                              \
        _Pragma("unroll")                                                       \
        for (int ni = 0; ni < 4; ++ni)                                          \
            acc[4 + mi][ni] = __builtin_amdgcn_mfma_f32_16x16x32_f16(           \
                aw[mi], bv[ni], acc[4 + mi][ni], 0, 0, 0);                      \
    __builtin_amdgcn_s_setprio(0);                                              \
    cur = (cur == 2) ? 0 : cur + 1;                                             \
    stg = (stg == 2) ? 0 : stg + 1;                                             \
  }

__global__ __launch_bounds__(256, 2) void versor_gemm_qkv2(
    const short* __restrict__ Xf,       // A: 2048 x 4096
    const short* __restrict__ WmT3,     // B: 12288 x 4096 (q,k,v stacked)
    short* __restrict__ OQ,
    short* __restrict__ OK,
    short* __restrict__ OV)
{
    extern __shared__ short lds[];   // 3 bufs x (A 8192 | B 4096) shorts

    const int tid  = threadIdx.x;
    const int lane = tid & 63;
    const int wid  = tid >> 6;        // 0..3
    const int wm   = wid >> 1;        // 0..1  (128-row half)
    const int wn   = wid & 1;         // 0..1  (64-col half)

    // XCD ownership swizzle: grid (96, 8); xcd owns 12 col-panels, row-fast
    const int wg  = blockIdx.x + blockIdx.y * 96;
    const int xcd = wg & 7;
    const int u   = wg >> 3;          // 0..95
    const int bm  = u & 7;
    const int bn  = xcd * 12 + (u >> 3);
    const int row0 = bm * 256;
    const int col0 = bn * 128;

    const int lda = 4096, ldb = 4096;

    // staging: A 256x32 = 16 chunks (4/wave), B 128x32 = 8 chunks (2/wave)
    const int jsw = ((lane & 3) ^ ((lane >> 3) & 3)) * 8;
    const short* gA0 = Xf + (size_t)(row0 + wid * 64 + (lane >> 2)) * lda + jsw;
    const short* gA1 = gA0 + (size_t)16 * lda;
    const short* gA2 = gA0 + (size_t)32 * lda;
    const short* gA3 = gA0 + (size_t)48 * lda;
    const short* gB0 = WmT3 + (size_t)(col0 + wid * 32 + (lane >> 2)) * ldb + jsw;
    const short* gB1 = gB0 + (size_t)16 * ldb;
    const int dA = wid * 4 * 512;            // A chunks at [0, 8192)
    const int dB = 8192 + wid * 2 * 512;     // B chunks at [8192, 12288)

    // ds_read frag bases (swizzled, lane-only XOR)
    const int swz = ((lane >> 4) ^ (((lane & 15) >> 1) & 3)) * 8;
    const int ard = (wm * 128 + (lane & 15)) * 32 + swz;          // + mi*512
    const int brd = 8192 + (wn * 64 + (lane & 15)) * 32 + swz;    // + ni*512

    f32x4 acc[8][4];
    #pragma unroll
    for (int i = 0; i < 8; ++i)
        #pragma unroll
        for (int j = 0; j < 4; ++j)
            acc[i][j] = (f32x4){0.f, 0.f, 0.f, 0.f};

    const int NT = 4096 >> 5;   // 128

    // prologue: stage tiles 0,1 into bufs 0,1 (6 gloads each / wave)
    #pragma unroll
    for (int pt = 0; pt < 2; ++pt){
        const int sb = pt * 12288;
        GLOAD_LDS(gA0 + pt * 32, lds + sb + dA + 0 * 512);
        GLOAD_LDS(gA1 + pt * 32, lds + sb + dA + 1 * 512);
        GLOAD_LDS(gA2 + pt * 32, lds + sb + dA + 2 * 512);
        GLOAD_LDS(gA3 + pt * 32, lds + sb + dA + 3 * 512);
        GLOAD_LDS(gB0 + pt * 32, lds + sb + dB + 0 * 512);
        GLOAD_LDS(gB1 + pt * 32, lds + sb + dB + 1 * 512);
    }

    int cur = 0, stg = 2;
    for (int t = 0; t < NT - 1; ++t)
        QKV_TILE(t, 6, (t + 2 < NT))
    QKV_TILE(NT - 1, 0, false)

    // ---------------- epilogue ----------------
    const int rb = row0 + wm * 128 + (lane >> 4) * 4;   // + mi*16 + j

    // normalize each 32-col blade group to unit RMS
    #pragma unroll
    for (int mi = 0; mi < 8; ++mi){
        #pragma unroll
        for (int g = 0; g < 2; ++g){
            f32x4 a0 = acc[mi][2 * g], a1 = acc[mi][2 * g + 1];
            f32x4 ss = a0 * a0 + a1 * a1;
            #pragma unroll
            for (int m = 1; m < 16; m <<= 1){
                ss.x += __shfl_xor(ss.x, m);
                ss.y += __shfl_xor(ss.y, m);
                ss.z += __shfl_xor(ss.z, m);
                ss.w += __shfl_xor(ss.w, m);
            }
            f32x4 inv;
            inv.x = 1.0f / sqrtf(ss.x * 0.03125f + 1e-6f);
            inv.y = 1.0f / sqrtf(ss.y * 0.03125f + 1e-6f);
            inv.z = 1.0f / sqrtf(ss.z * 0.03125f + 1e-6f);
            inv.w = 1.0f / sqrtf(ss.w * 0.03125f + 1e-6f);
            acc[mi][2 * g]     = a0 * inv;
            acc[mi][2 * g + 1] = a1 * inv;
        }
    }

    const int zsel = col0 >> 12;          // 0:Q 1:K 2:V
    const int cbm  = (col0 & 4095) + wn * 64 + (lane & 15);
    if (zsel == 0){
        const float sg0 = blade_sign(lane & 15, lane & 15);
        const float sg1 = blade_sign(16 | (lane & 15), 16 | (lane & 15));
        #pragma unroll
        for (int mi = 0; mi < 8; ++mi)
            #pragma unroll
            for (int ni = 0; ni < 4; ++ni){
                const f32x4 v = acc[mi][ni] * ((ni & 1) ? sg1 : sg0);
                #pragma unroll
                for (int j = 0; j < 4; ++j)
                    OQ[(size_t)(rb + mi * 16 + j) * 4096 + (cbm + ni * 16)] = f2h(v[j]);
            }
    } else if (zsel == 1){
        #pragma unroll
        for (int mi = 0; mi < 8; ++mi)
            #pragma unroll
            for (int ni = 0; ni < 4; ++ni)
                #pragma unroll
                for (int j = 0; j < 4; ++j)
                    OK[(size_t)(rb + mi * 16 + j) * 4096 + (cbm + ni * 16)] = f2h(acc[mi][ni][j]);
    } else {
        // V^T store: (b,h,f,t), 4 consecutive t per lane
        #pragma unroll
        for (int mi = 0; mi < 8; ++mi){
            const int r = rb + mi * 16;
            const int b = r >> 10, tt = r & 1023;
            #pragma unroll
            for (int ni = 0; ni < 4; ++ni){
                const int c = cbm + ni * 16;
                const int h = c >> 9, f = c & 511;
                s16x4 pv;
                #pragma unroll
                for (int j = 0; j < 4; ++j) pv[j] = f2h(acc[mi][ni][j]);
                *reinterpret_cast<s16x4*>(OV + ((size_t)((b * 8 + h) * 512 + f)) * 1024 + tt) = pv;
            }
        }
    }
}

// =======================================================================
// 128x128 ring-3 pipelined GEMM (proven R6/R7): BK=32, 4 waves, 48 KB LDS
// -> 3 blocks/CU. vmcnt(4) counted, peeled tail. XOR swizzle. setprio.
// EPI: 3 = final (norm, f32)    5 = PV (f16, batched over z)
// =======================================================================
#define R3_TILE(T, WN, PF)                                                      \
  {                                                                             \
    const int bb = cur * 8192;                                                  \
    wait_vm(WN);                                                                \
    __builtin_amdgcn_s_barrier();                                               \
    asm volatile("" ::: "memory");                                              \
    __builtin_amdgcn_sched_barrier(0);                                          \
    const int sb = stg * 8192;                                                  \
    if (PF){                                                                    \
        GLOAD_LDS(gA0 + (size_t)((T) + 2) * 32, lds + sb + dA0);                \
        GLOAD_LDS(gA1 + (size_t)((T) + 2) * 32, lds + sb + dA1);                \
    }                                                                           \
    f16x8 av[4], bv[4];                                                         \
    _Pragma("unroll")                                                           \
    for (int i = 0; i < 4; ++i)                                                 \
        av[i] = *reinterpret_cast<const f16x8*>(lds + bb + ard + i * 512);      \
    bv[0] = *reinterpret_cast<const f16x8*>(lds + bb + brd + 0 * 512);          \
    bv[1] = *reinterpret_cast<const f16x8*>(lds + bb + brd + 1 * 512);          \
    __builtin_amdgcn_s_setprio(1);                                              \
    _Pragma("unroll")                                                           \
    for (int mi = 0; mi < 4; ++mi)                                              \
        _Pragma("unroll")                                                       \
        for (int ni = 0; ni < 2; ++ni)                                          \
            acc[mi][ni] = __builtin_amdgcn_mfma_f32_16x16x32_f16(               \
                av[mi], bv[ni], acc[mi][ni], 0, 0, 0);                          \
    __builtin_amdgcn_s_setprio(0);                                              \
    if (PF){                                                                    \
        GLOAD_LDS(gB0 + (size_t)((T) + 2) * 32, lds + sb + dB0);                \
        GLOAD_LDS(gB1 + (size_t)((T) + 2) * 32, lds + sb + dB1);                \
    }                                                                           \
    bv[2] = *reinterpret_cast<const f16x8*>(lds + bb + brd + 2 * 512);          \
    bv[3] = *reinterpret_cast<const f16x8*>(lds + bb + brd + 3 * 512);          \
    __builtin_amdgcn_s_setprio(1);                                              \
    _Pragma("unroll")                                                           \
    for (int mi = 0; mi < 4; ++mi)                                              \
        _Pragma("unroll")                                                       \
        for (int ni = 2; ni < 4; ++ni)                                          \
            acc[mi][ni] = __builtin_amdgcn_mfma_f32_16x16x32_f16(               \
                av[mi], bv[ni], acc[mi][ni], 0, 0, 0);                          \
    __builtin_amdgcn_s_setprio(0);                                              \
    cur = (cur == 2) ? 0 : cur + 1;                                             \
    stg = (stg == 2) ? 0 : stg + 1;                                             \
  }

template<int EPI, int CPX>
__global__ __launch_bounds__(256, 3) void versor_gemm_r3(
    const short* __restrict__ Abase, int lda,
    const short* __restrict__ Bbase, int ldb,
    int K, void* __restrict__ OutP,
    short* __restrict__ OQ, short* __restrict__ OK, short* __restrict__ OV)
{
    __shared__ short lds[3 * 8192];

    const int tid  = threadIdx.x;
    const int lane = tid & 63;
    const int wid  = tid >> 6;
    const int wr   = wid >> 1;
    const int wc   = wid & 1;
    const int z    = blockIdx.z;

    int bn, bm;
    if constexpr (CPX > 0){
        const int wg  = blockIdx.x + blockIdx.y * gridDim.x;
        const int xcd = wg & 7;
        const int u   = wg >> 3;
        bm = u & 15;
        bn = xcd * CPX + (u >> 4);
    } else {
        bn = blockIdx.x; bm = blockIdx.y;
    }

    const short* A = Abase;
    const short* B = Bbase;
    if constexpr (EPI == 5){
        A += (size_t)z * 1024 * 2048;
        B += (size_t)z * 512 * 1024;
    }
    const int row0 = bm * 128;
    const int col0 = bn * 128;

    const int jsw = ((lane & 3) ^ ((lane >> 3) & 3)) * 8;
    const short* gA0 = A + (size_t)(row0 + wid * 16 + (lane >> 2)) * lda + jsw;
    const short* gA1 = gA0 + (size_t)64 * lda;
    const short* gB0 = B + (size_t)(col0 + wid * 16 + (lane >> 2)) * ldb + jsw;
    const short* gB1 = gB0 + (size_t)64 * ldb;
    const int dA0 = wid * 512,        dA1 = 2048 + wid * 512;
    const int dB0 = 4096 + wid * 512, dB1 = 6144 + wid * 512;

    const int swz = ((lane >> 4) ^ (((lane & 15) >> 1) & 3)) * 8;
    const int ard = (wr * 64 + (lane & 15)) * 32 + swz;
    const int brd = 4096 + (wc * 64 + (lane & 15)) * 32 + swz;

    f32x4 acc[4][4];
    #pragma unroll
    for (int i = 0; i < 4; ++i)
        #pragma unroll
        for (int j = 0; j < 4; ++j)
            acc[i][j] = (f32x4){0.f, 0.f, 0.f, 0.f};

    const int NT = K >> 5;

    #pragma unroll
    for (int pt = 0; pt < 2; ++pt){
        const int sb = pt * 8192;
        GLOAD_LDS(gA0 + pt * 32, lds + sb + dA0);
        GLOAD_LDS(gA1 + pt * 32, lds + sb + dA1);
        GLOAD_LDS(gB0 + pt * 32, lds + sb + dB0);
        GLOAD_LDS(gB1 + pt * 32, lds + sb + dB1);
    }

    int cur = 0, stg = 2;
    for (int t = 0; t < NT - 1; ++t)
        R3_TILE(t, 4, (t + 2 < NT))
    R3_TILE(NT - 1, 0, false)

    const int rb = row0 + wr * 64 + (lane >> 4) * 4;
    const int cb = col0 + wc * 64 + (lane & 15);

    if constexpr (EPI == 3){
        #pragma unroll
        for (int mi = 0; mi < 4; ++mi){
            #pragma unroll
            for (int g = 0; g < 2; ++g){
                f32x4 a0 = acc[mi][2 * g], a1 = acc[mi][2 * g + 1];
                f32x4 ss = a0 * a0 + a1 * a1;
                #pragma unroll
                for (int m = 1; m < 16; m <<= 1){
                    ss.x += __shfl_xor(ss.x, m);
                    ss.y += __shfl_xor(ss.y, m);
                    ss.z += __shfl_xor(ss.z, m);
                    ss.w += __shfl_xor(ss.w, m);
                }
                f32x4 inv;
                inv.x = 1.0f / sqrtf(ss.x * 0.03125f + 1e-6f);
                inv.y = 1.0f / sqrtf(ss.y * 0.03125f + 1e-6f);
                inv.z = 1.0f / sqrtf(ss.z * 0.03125f + 1e-6f);
                inv.w = 1.0f / sqrtf(ss.w * 0.03125f + 1e-6f);
                acc[mi][2 * g]     = a0 * inv;
                acc[mi][2 * g + 1] = a1 * inv;
            }
        }
        float* Of = (float*)OutP;
        #pragma unroll
        for (int mi = 0; mi < 4; ++mi)
            #pragma unroll
            for (int ni = 0; ni < 4; ++ni)
                #pragma unroll
                for (int j = 0; j < 4; ++j)
                    Of[(size_t)(rb + mi * 16 + j) * 4096 + (cb + ni * 16)] = acc[mi][ni][j];
    }
    if constexpr (EPI == 5){
        short* Ob = (short*)OutP;
        const int b = z >> 3, h = z & 7;
        #pragma unroll
        for (int mi = 0; mi < 4; ++mi)
            #pragma unroll
            for (int ni = 0; ni < 4; ++ni)
                #pragma unroll
                for (int j = 0; j < 4; ++j)
                    Ob[(size_t)(b * 1024 + rb + mi * 16 + j) * 4096 + h * 512 + (cb + ni * 16)]
                        = f2h(acc[mi][ni][j]);
    }
    (void)OQ; (void)OK; (void)OV;
}

// =======================================================================
// Scores kernel (256x256, 8 waves, ring-4, dyn 128KB LDS) with torque
// epilogue. Peeled tail (vmcnt 8 -> 4 -> 0).
// =======================================================================
#define SC_TILE(T, WN, PF)                                                      \
  {                                                                             \
    const int bb = ((T) & 3) * 16384;                                           \
    wait_vm(WN);                                                                \
    __builtin_amdgcn_s_barrier();                                               \
    asm volatile("" ::: "memory");                                              \
    __builtin_amdgcn_sched_barrier(0);                                          \
    if (PF){                                                                    \
        const int nb = (((T) + 3) & 3) * 16384;                                 \
        GLOAD_LDS(gA0 + (size_t)((T) + 3) * 32, lds + nb + dA0);                \
        GLOAD_LDS(gA1 + (size_t)((T) + 3) * 32, lds + nb + dA1);                \
    }                                                                           \
    f16x8 av[4], bv[4];                                                         \
    _Pragma("unroll")                                                           \
    for (int i = 0; i < 4; ++i){                                                \
        av[i] = *reinterpret_cast<const f16x8*>(lds + bb + ard + i * 512);      \
        bv[i] = *reinterpret_cast<const f16x8*>(lds + bb + brd + i * 512);      \
    }                                                                           \
    __builtin_amdgcn_s_setprio(1);                                              \
    _Pragma("unroll")                                                           \
    for (int mi = 0; mi < 4; ++mi)                                              \
        _Pragma("unroll")                                                       \
        for (int ni = 0; ni < 4; ++ni)                                          \
            acc[mi][ni] = __builtin_amdgcn_mfma_f32_16x16x32_f16(               \
                av[mi], bv[ni], acc[mi][ni], 0, 0, 0);                          \
    __builtin_amdgcn_s_setprio(0);                                              \
    if (PF){                                                                    \
        const int nb = (((T) + 3) & 3) * 16384;                                 \
        GLOAD_LDS(gB0 + (size_t)((T) + 3) * 32, lds + nb + dB0);                \
        GLOAD_LDS(gB1 + (size_t)((T) + 3) * 32, lds + nb + dB1);                \
    }                                                                           \
    f16x8 aw[4];                                                                \
    _Pragma("unroll")                                                           \
    for (int i = 0; i < 4; ++i)                                                 \
        aw[i] = *reinterpret_cast<const f16x8*>(lds + bb + ard + (4 + i) * 512);\
    __builtin_amdgcn_s_setprio(1);                                              \
    _Pragma("unroll")                                                           \
    for (int mi = 0; mi < 4; ++mi)                                              \
        _Pragma("unroll")                                                       \
        for (int ni = 0; ni < 4; ++ni)                                          \
            acc[4 + mi][ni] = __builtin_amdgcn_mfma_f32_16x16x32_f16(           \
                aw[mi], bv[ni], acc[4 + mi][ni], 0, 0, 0);                      \
    __builtin_amdgcn_s_setprio(0);                                              \
  }

__global__ __launch_bounds__(512, 2) void versor_gemm_sc(
    const short* __restrict__ Qbase, const short* __restrict__ Kbase,
    int K, float* __restrict__ OutP,
    const float* __restrict__ NqP, const float* __restrict__ NkP,
    const float* __restrict__ LamP)
{
    extern __shared__ short lds[];

    const int tid  = threadIdx.x;
    const int lane = tid & 63;
    const int wid  = tid >> 6;
    const int wm   = wid >> 2;
    const int wn   = wid & 3;
    const int z    = blockIdx.z;

    const int b = z >> 3, h = z & 7;
    const size_t off = (size_t)b * 1024 * 4096 + (size_t)h * 512;
    const short* A = Qbase + off;
    const short* B = Kbase + off;
    const int lda = 4096, ldb = 4096;
    const int row0 = blockIdx.y * 256;
    const int col0 = blockIdx.x * 256;

    const int jsw = ((lane & 3) ^ ((lane >> 3) & 3)) * 8;
    const short* gA0 = A + (size_t)(row0 + wid * 32 + (lane >> 2)) * lda + jsw;
    const short* gA1 = gA0 + (size_t)16 * lda;
    const short* gB0 = B + (size_t)(col0 + wid * 32 + (lane >> 2)) * ldb + jsw;
    const short* gB1 = gB0 + (size_t)16 * ldb;
    const int dA0 = wid * 1024, dA1 = dA0 + 512;
    const int dB0 = 8192 + wid * 1024, dB1 = dB0 + 512;

    const int swz = ((lane >> 4) ^ (((lane & 15) >> 1) & 3)) * 8;
    const int ard = (wm * 128 + (lane & 15)) * 32 + swz;
    const int brd = 8192 + (wn * 64 + (lane & 15)) * 32 + swz;

    f32x4 acc[8][4];
    #pragma unroll
    for (int i = 0; i < 8; ++i)
        #pragma unroll
        for (int j = 0; j < 4; ++j)
            acc[i][j] = (f32x4){0.f, 0.f, 0.f, 0.f};

    const int NT = K >> 5;   // 16

    #pragma unroll
    for (int pt = 0; pt < 3; ++pt){
        const int bb = pt * 16384;
        GLOAD_LDS(gA0 + pt * 32, lds + bb + dA0);
        GLOAD_LDS(gA1 + pt * 32, lds + bb + dA1);
        GLOAD_LDS(gB0 + pt * 32, lds + bb + dB0);
        GLOAD_LDS(gB1 + pt * 32, lds + bb + dB1);
    }

    for (int t = 0; t < NT - 2; ++t)
        SC_TILE(t, 8, (t + 3 < NT))
    SC_TILE(NT - 2, 4, false)
    SC_TILE(NT - 1, 0, false)

    const int rb = row0 + wm * 128 + (lane >> 4) * 4;
    const int cb = col0 + wn * 64 + (lane & 15);

    float* Of = OutP + (size_t)z * 1024 * 1024;
    const float lam = *LamP;
    const float* nq = NqP + z * 1024;
    const float* nk = NkP + z * 1024;
    #pragma unroll
    for (int mi = 0; mi < 8; ++mi)
        #pragma unroll
        for (int j = 0; j < 4; ++j){
            const int r = rb + mi * 16 + j;
            const float qn = nq[r];
            #pragma unroll
            for (int ni = 0; ni < 4; ++ni){
                const int c = cb + ni * 16;
                const float sc = acc[mi][ni][j];
                const float tq = sqrtf(fmaxf(qn * nk[c] - sc * sc, 0.0f) + 1e-6f);
                Of[(size_t)r * 1024 + c] = 0.25f * (sc + lam * tq);
            }
        }
}

// =======================================================================
extern "C" void kernel_launch(void* const* d_in, const int* in_sizes, int n_in,
                              void* d_out, int out_size, void* d_ws, size_t ws_size,
                              hipStream_t stream)
{
    (void)in_sizes; (void)n_in; (void)out_size; (void)ws_size;
    const float* x   = (const float*)d_in[0];
    const float* Wq  = (const float*)d_in[1];
    const float* Wk  = (const float*)d_in[2];
    const float* Wv  = (const float*)d_in[3];
    const float* Wo  = (const float*)d_in[4];
    const float* lam = (const float*)d_in[5];
    float* out = (float*)d_out;
    char*  ws  = (char*)d_ws;

    // workspace layout (~160.2 MB peak)
    short* Xf   = (short*)(ws);                             // 16 MB; later attn-out
    short* WmT3 = (short*)(ws + (16u  << 20));              // 96 MB (q,k,v); dead after QKV
    short* Qf   = (short*)(ws + (112u << 20));              // 16 MB
    short* Kf   = (short*)(ws + (128u << 20));              // 16 MB
    short* Vt   = (short*)(ws + (144u << 20));              // 16 MB (B,H,512,1024) f16
    float* Nq   = (float*)(ws + (160u << 20));              // 64 KB
    float* Nk   = (float*)(ws + (160u << 20) + (64u << 10));// 64 KB
    float* Sc   = (float*)(ws + (16u  << 20));              // 64 MB, overlays WmT3[0:64MB]
    short* WmTo = (short*)(ws + (80u  << 20));              // 32 MB, overlays WmT3[64:96MB]
    short* Attn = Xf;                                       // 16 MB, overlays Xf

    const int SC_LDS  = 131072;
    const int QKV_LDS = 73728;
    hipFuncSetAttribute(reinterpret_cast<const void*>(versor_gemm_sc),
                        hipFuncAttributeMaxDynamicSharedMemorySize, SC_LDS);
    hipFuncSetAttribute(reinterpret_cast<const void*>(versor_gemm_qkv2),
                        hipFuncAttributeMaxDynamicSharedMemorySize, QKV_LDS);

    dim3 blk(256), blk8(512);
    cast_f32_f16<<<4096, blk, 0, stream>>>(x, Xf);

    dim3 gw3(8192, 3);
    build_wmat3<<<gw3, blk, 0, stream>>>(Wq, Wk, Wv, WmT3);

    // fused QKV: 256x128 tiles, grid (96 cols, 8 rows) = 768 blocks @ 2/CU
    dim3 gqkv(96, 8, 1);
    versor_gemm_qkv2<<<gqkv, blk, QKV_LDS, stream>>>(Xf, WmT3, Qf, Kf, Vt);

    row_norms<<<4096, blk, 0, stream>>>(Qf, Kf, Nq, Nk);

    build_wmat<<<8192, blk, 0, stream>>>(Wo, WmTo);

    dim3 gsc(4, 4, 16);      // 256 blocks, 1/CU
    versor_gemm_sc<<<gsc, blk8, SC_LDS, stream>>>(Qf, Kf, 512, Sc, Nq, Nk, lam);
    softmax_rows<<<4096, blk, 0, stream>>>(Sc);

    dim3 gpv(4, 8, 16);      // 512 blocks
    versor_gemm_r3<5, 0><<<gpv, blk, 0, stream>>>(
        (const short*)Sc, 2048, Vt, 1024, 1024, Attn, nullptr, nullptr, nullptr);

    dim3 gfin(32, 16, 1);    // 512 blocks, XCD swizzle CPX=4
    versor_gemm_r3<3, 4><<<gfin, blk, 0, stream>>>(
        Attn, 4096, WmTo, 4096, 4096, out, nullptr, nullptr, nullptr);
}